// Round 8
// baseline (177.119 us; speedup 1.0000x reference)
//
#include <hip/hip_runtime.h>
#include <hip/hip_bf16.h>
#include <math.h>

#define NN 2048
#define CHAIN 512
#define KNN 30
#define LRK 10
#define NFIX 40
#define NSLOT 42
#define AGPAD 260
#define NREL 1023

#define OUT_ROT 0
#define OUT_TRANS (NN*9)
#define OUT_BB (NN*9 + NN*3)

#define THREEFRY_PARTITIONABLE 1

__device__ __forceinline__ int xcd_swz(int b){ return ((b & 7) << 8) | (b >> 3); }

// ---------------- threefry2x32, key = (0, 42) ----------------
__device__ __forceinline__ unsigned rotl32(unsigned x, unsigned r){ return (x<<r)|(x>>(32u-r)); }

__device__ __forceinline__ void tf_block(unsigned &x0, unsigned &x1){
  const unsigned k0 = 0u, k1 = 42u, k2 = 0x1BD11BDAu ^ 0u ^ 42u;
  x0 += k0; x1 += k1;
#define TFR(a) x0 += x1; x1 = rotl32(x1,(a)); x1 ^= x0;
  TFR(13) TFR(15) TFR(26) TFR(6)   x0 += k1; x1 += k2 + 1u;
  TFR(17) TFR(29) TFR(16) TFR(24)  x0 += k2; x1 += k0 + 2u;
  TFR(13) TFR(15) TFR(26) TFR(6)   x0 += k0; x1 += k1 + 3u;
  TFR(17) TFR(29) TFR(16) TFR(24)  x0 += k1; x1 += k2 + 4u;
  TFR(13) TFR(15) TFR(26) TFR(6)   x0 += k2; x1 += k0 + 5u;
#undef TFR
}

__device__ __forceinline__ float gumbel_from_bits(unsigned bits){
  float f = __uint_as_float((bits >> 9) | 0x3f800000u) - 1.0f;
  const float tiny = 1.17549435e-38f;
  float u = fmaxf(tiny, f * (1.0f - tiny) + tiny);
  return -logf(-logf(u));
}

__device__ __forceinline__ float gumbel_at(unsigned p){
#if THREEFRY_PARTITIONABLE
  unsigned x0 = 0u, x1 = p;
  tf_block(x0, x1);
  return gumbel_from_bits(x0 ^ x1);
#else
  const unsigned HALF = (NN*(unsigned)NN)/2u;
  unsigned c0, c1; bool lo = p < HALF;
  if(lo){ c0 = p; c1 = p + HALF; } else { c0 = p - HALF; c1 = p; }
  tf_block(c0, c1);
  return gumbel_from_bits(lo ? c0 : c1);
#endif
}

// ---------------- K1: fused topk / prep / Trel / Wot (block-role split) ------------
__global__ __launch_bounds__(256) void k_pretop(
    const float* __restrict__ rots, const float* __restrict__ trans,
    const float* __restrict__ nf, const float* __restrict__ Wa1,
    const float* __restrict__ Wv, const float* __restrict__ Wo,
    const int* __restrict__ xmask, const int* __restrict__ nmask,
    float* __restrict__ P, float* __restrict__ U, float* __restrict__ V,
    int* __restrict__ srcs, float* __restrict__ Trel, float* __restrict__ Wot)
{
  __shared__ __align__(16) char smem[4*4*132*4];
  int bb = blockIdx.x, t = threadIdx.x;

  if(bb >= NN + 1024){
    // ---------------- Wot role: Wot[k][u] = Wo[u][k] ----------------
    int b2 = bb - (NN + 1024);        // 0..15
    int i0 = b2*8192;
    for(int i = i0 + t; i < i0 + 8192; i += 256){
      int kk2 = i >> 8, uu = i & 255;
      Wot[i] = Wo[uu*128 + kk2];
    }
    return;
  }

  if(bb >= NN + 512){
    // ---------------- Trel role ----------------
    int r = (bb - (NN+512))*2 + (t >> 7);
    int k = t & 127;
    if(r < NREL){
      float rel = (float)(r - 511);
      float acc = 0.f;
#pragma unroll
      for(int j=0;j<8;j++){
        float fr = expf((float)(2*j) * (float)(-0.5756462732485115));
        float ang = rel * fr;
        acc += cosf(ang) * Wa1[(278+j)*128 + k];
        acc += sinf(ang) * Wa1[(286+j)*128 + k];
      }
      Trel[r*128 + k] = acc;
    }
    return;
  }

  if(bb < NN){
    // ---------------- topk role ----------------
    unsigned* s_kk = (unsigned*)smem;          // [512]
    unsigned* s_lk = s_kk + CHAIN;             // [512]
    int i = bb;
    int base = (i >> 9) << 9;
    float tx = trans[i*3+0], ty = trans[i*3+1], tz = trans[i*3+2];
    for(int q=t; q<CHAIN; q+=256){
      int j = base + q;
      float dx = __fsub_rn(trans[j*3+0], tx);
      float dy = __fsub_rn(trans[j*3+1], ty);
      float dz = __fsub_rn(trans[j*3+2], tz);
      float d2 = __fadd_rn(__fadd_rn(__fmul_rn(dx,dx),__fmul_rn(dy,dy)),__fmul_rn(dz,dz));
      bool val = (j != i);
      float dm = val ? d2 : 1e30f;
      s_kk[q] = __float_as_uint(dm) ^ 0x80000000u;
      if(val){
        float g = gumbel_at((unsigned)(i*NN + j));
        float sc = __fadd_rn(__fmul_rn(-1.5f, logf(dm)), g);
        unsigned b = __float_as_uint(sc);
        unsigned ord = b ^ ((b & 0x80000000u) ? 0xFFFFFFFFu : 0x80000000u);
        s_lk[q] = ~ord;
      } else {
        s_lk[q] = 0xFFFFFFFFu;
      }
    }
    __syncthreads();
    if(t < 128){
      int w = t >> 6, lane = t & 63;
      unsigned* arr = w ? s_lk : s_kk;
      int K = w ? LRK : KNN;
      int outoff = w ? KNN : 0;
      unsigned long long best = ~0ull;
      for(int q=lane; q<CHAIN; q+=64){
        unsigned long long kk = ((unsigned long long)arr[q]<<32) | (unsigned)q;
        if(kk < best) best = kk;
      }
      for(int k=0;k<K;k++){
        unsigned long long r = best;
        for(int off=32; off; off>>=1){
          unsigned long long o = __shfl_xor(r, off, 64);
          if(o < r) r = o;
        }
        int winq = (int)(unsigned)(r & 0xffffffffull);
        if(lane == 0){
          srcs[i*NFIX + outoff + k] = base + winq;
          arr[winq] = 0xFFFFFFFFu;
        }
        asm volatile("s_waitcnt lgkmcnt(0)" ::: "memory");
        __builtin_amdgcn_wave_barrier();
        if((winq & 63) == lane){
          best = ~0ull;
          for(int q=lane; q<CHAIN; q+=64){
            unsigned long long kk = ((unsigned long long)arr[q]<<32) | (unsigned)q;
            if(kk < best) best = kk;
          }
        }
      }
    }
    return;
  }

  // ---------------- prep role (4 nodes) ----------------
  float (*fr)[4][132] = (float (*)[4][132])smem;
  int n0 = (bb - NN)*4;
  for(int i=t; i<2048; i+=256){
    int nd = i>>9, c = (i>>7)&3, kk = i&127;
    fr[nd][c][kk] = nf[(n0+nd)*512 + c*128 + kk];
  }
  if(t < 4){
    fr[t][0][128] = 0.0f; fr[t][0][129] = 0.0f;
    fr[t][0][130] = (nmask[n0+t] != 0 && xmask[n0+t] == 0) ? 1.0f : 0.0f;
  } else if(t >= 16 && t < 52){
    int q = t - 16; int nd = q/9, r = q%9, a = r/3, i = r%3;
    int n = n0 + nd;
    const float BB[3][3] = {{-0.525f,1.363f,0.0f},{0.f,0.f,0.f},{1.526f,0.f,0.f}};
    float bb_ = rots[n*9+i*3+0]*BB[a][0] + rots[n*9+i*3+1]*BB[a][1]
              + rots[n*9+i*3+2]*BB[a][2] + trans[n*3+i];
    fr[nd][1+i][128+a] = bb_;
  }
  __syncthreads();

  float a[4][4];
#pragma unroll
  for(int nd=0;nd<4;nd++)
#pragma unroll
    for(int c=0;c<4;c++) a[nd][c]=0.f;
  for(int j=0;j<128;j+=4){
    float w0=Wv[(j+0)*256+t], w1=Wv[(j+1)*256+t], w2=Wv[(j+2)*256+t], w3=Wv[(j+3)*256+t];
#pragma unroll
    for(int nd=0;nd<4;nd++){
#pragma unroll
      for(int c=0;c<4;c++){
        float4 f4 = *(const float4*)&fr[nd][c][j];
        a[nd][c] += f4.x*w0 + f4.y*w1 + f4.z*w2 + f4.w*w3;
      }
    }
  }
  for(int j=128;j<131;j++){
    float w = Wv[j*256+t];
#pragma unroll
    for(int nd=0;nd<4;nd++)
#pragma unroll
      for(int c=0;c<4;c++) a[nd][c] += fr[nd][c][j]*w;
  }
#pragma unroll
  for(int nd=0;nd<4;nd++){
    float4 v4; v4.x=a[nd][0]; v4.y=a[nd][1]; v4.z=a[nd][2]; v4.w=a[nd][3];
    *(float4*)&P[(n0+nd)*1024 + t*4] = v4;   // layout [n][u][c]
  }

  int k = t & 127;
  int isV = t >> 7;
  const float* Wcol = Wa1 + (isV ? 131*128 : 0);
  float u[4] = {0.f,0.f,0.f,0.f};
  for(int j=0;j<128;j+=4){
    float w0=Wcol[(j+0)*128+k], w1=Wcol[(j+1)*128+k], w2=Wcol[(j+2)*128+k], w3=Wcol[(j+3)*128+k];
#pragma unroll
    for(int nd=0;nd<4;nd++){
      float4 f4 = *(const float4*)&fr[nd][0][j];
      u[nd] += f4.x*w0 + f4.y*w1 + f4.z*w2 + f4.w*w3;
    }
  }
  for(int j=128;j<131;j++){
    float w = Wcol[j*128+k];
#pragma unroll
    for(int nd=0;nd<4;nd++) u[nd] += fr[nd][0][j]*w;
  }
  float* OUT = isV ? V : U;
#pragma unroll
  for(int nd=0;nd<4;nd++) OUT[(n0+nd)*128 + k] = u[nd];
}

// ---------------- K3: edge MLP + logits via wave-reduce + softmax + agg + @Wot ----
// LDS ~7.3KB -> occupancy bound by VGPR/waves, not LDS.
__global__ __launch_bounds__(256) void k_attn(
    const float* __restrict__ trans, const float* __restrict__ Wa1,
    const float* __restrict__ ba1, const float* __restrict__ Wa2,
    const float* __restrict__ Wot,
    const float* __restrict__ U, const float* __restrict__ V,
    const float* __restrict__ P, const float* __restrict__ Trel,
    const int* __restrict__ srcs, float* __restrict__ Y)
{
  __shared__ int   s_src[NSLOT];
  __shared__ int   s_val[NSLOT];
  __shared__ float s_dist[NSLOT];
  __shared__ __align__(16) float s_mux[1344];  // rbf[42*16] | part[42*16]  ->  agg[4][260]
  __shared__ float s_att[NSLOT*8];

  float* s_rbf  = s_mux;          // [e*16+f]
  float* s_part = s_mux + 672;    // [e*16 + kw*8 + h]

  int b = blockIdx.x, t = threadIdx.x;
  int d = xcd_swz(b);
  int pos = d & (CHAIN-1);
  int k = t & 127, grp = t >> 7;
  int lane = t & 63, kw = (t >> 6) & 1;

  // stage 0: edge meta
  if(t < NSLOT){
    int src;
    if(t < NFIX)      src = srcs[d*NFIX + t];
    else if(t == NFIX) src = (pos > 0)       ? d-1 : d;
    else               src = (pos < CHAIN-1) ? d+1 : d;
    s_src[t] = src;
    float dx = trans[src*3+0]-trans[d*3+0];
    float dy = trans[src*3+1]-trans[d*3+1];
    float dz = trans[src*3+2]-trans[d*3+2];
    float dist = sqrtf(dx*dx + dy*dy + dz*dz + 1e-12f);
    s_dist[t] = dist;
    s_val[t] = (dist > 1e-3f) ? 1 : 0;
  }

  // per-thread register state (k fixed per thread)
  float wreg[16];
#pragma unroll
  for(int f=0; f<16; f++) wreg[f] = Wa1[(262+f)*128 + k];
  float4 wa2a = *(const float4*)(Wa2 + k*8);
  float4 wa2b = *(const float4*)(Wa2 + k*8 + 4);
  float ubias = ba1[k] + V[d*128 + k];
  int hmine = ((lane&1)<<2) | (lane&2) | ((lane>>2)&1);
  __syncthreads();

  // stage 1: rbf[42][16]
  for(int i=t; i<NSLOT*16; i+=256){
    int e = i >> 4, f = i & 15;
    float zz = (s_dist[e] - (float)f * (20.0f/15.0f)) * 0.8f;
    s_rbf[i] = expf(-(zz*zz));
  }
  __syncthreads();

  // stage 2: H[e][k] in-register, reduce H.Wa2 over the wave (17-shfl halving butterfly)
  for(int e = grp; e < NSLOT; e += 2){
    int src = s_src[e];
    float h = ubias + U[src*128 + k] + Trel[(src - d + 511)*128 + k];
    const float4* rp = (const float4*)(s_rbf + e*16);
#pragma unroll
    for(int q=0; q<4; q++){
      float4 ev = rp[q];
      h += ev.x*wreg[4*q+0] + ev.y*wreg[4*q+1] + ev.z*wreg[4*q+2] + ev.w*wreg[4*q+3];
    }
    h = (h >= 0.0f) ? h : 0.01f*h;
    // p[j] = H * Wa2[k][j]
    float p0 = h*wa2a.x, p1 = h*wa2a.y, p2 = h*wa2a.z, p3 = h*wa2a.w;
    float p4 = h*wa2b.x, p5 = h*wa2b.y, p6 = h*wa2b.z, p7 = h*wa2b.w;
    // step 1 (xor 1): 8 -> 4
    float q0=__shfl_xor(p0,1,64), q1=__shfl_xor(p1,1,64), q2=__shfl_xor(p2,1,64), q3=__shfl_xor(p3,1,64);
    float q4=__shfl_xor(p4,1,64), q5=__shfl_xor(p5,1,64), q6=__shfl_xor(p6,1,64), q7=__shfl_xor(p7,1,64);
    float r0,r1,r2,r3;
    if((lane&1)==0){ r0=p0+q0; r1=p1+q1; r2=p2+q2; r3=p3+q3; }
    else           { r0=p4+q4; r1=p5+q5; r2=p6+q6; r3=p7+q7; }
    // step 2 (xor 2): 4 -> 2
    q0=__shfl_xor(r0,2,64); q1=__shfl_xor(r1,2,64); q2=__shfl_xor(r2,2,64); q3=__shfl_xor(r3,2,64);
    float s0,s1;
    if((lane&2)==0){ s0=r0+q0; s1=r1+q1; }
    else           { s0=r2+q2; s1=r3+q3; }
    // step 3 (xor 4): 2 -> 1
    q0=__shfl_xor(s0,4,64); q1=__shfl_xor(s1,4,64);
    float v = ((lane&4)==0) ? (s0+q0) : (s1+q1);
    // steps 4-6: reduce over remaining lane groups
    v += __shfl_xor(v, 8, 64);
    v += __shfl_xor(v, 16, 64);
    v += __shfl_xor(v, 32, 64);
    if(lane < 8) s_part[e*16 + kw*8 + hmine] = v;
  }
  __syncthreads();

  // stage 3+4: softmax with inline logit assembly (t<64; lane=(g,h))
  if(t < 64){
    int h = t & 7, g = t >> 3;
    float m = -INFINITY;
    for(int e=g; e<NSLOT; e+=8){
      float l = s_part[e*16 + h] + s_part[e*16 + 8 + h];
      l = s_val[e] ? l : -1e30f;
      m = fmaxf(m, l);
    }
    for(int off=8; off<64; off<<=1) m = fmaxf(m, __shfl_xor(m, off, 64));
    m = (m > -5e29f) ? m : 0.0f;
    float z = 0.0f;
    for(int e=g; e<NSLOT; e+=8){
      float l = s_part[e*16 + h] + s_part[e*16 + 8 + h];
      l = s_val[e] ? l : -1e30f;
      float p = expf(l - m);
      s_att[e*8+h] = p; z += p;
    }
    for(int off=8; off<64; off<<=1) z += __shfl_xor(z, off, 64);
    float inv = 1.0f / (z + 1e-9f);
    for(int e=g; e<NSLOT; e+=8) s_att[e*8+h] *= inv;
  }
  __syncthreads();

  // stage 5: agg[u=t][c] = sum_e attn[e][u>>5] * P[src][u][c], 1-deep pipelined
  {
    int h = t >> 5;
    float a0=0.f,a1=0.f,a2=0.f,a3=0.f;
    float4 pn = *(const float4*)(P + (size_t)s_src[0]*1024 + t*4);
    float wn = s_att[h];
    for(int e=0;e<NSLOT;e++){
      float4 pc = pn; float wc = wn;
      if(e+1 < NSLOT){
        pn = *(const float4*)(P + (size_t)s_src[e+1]*1024 + t*4);
        wn = s_att[(e+1)*8 + h];
      }
      a0 += wc*pc.x; a1 += wc*pc.y; a2 += wc*pc.z; a3 += wc*pc.w;
    }
    __syncthreads();   // ensure softmax readers done with s_part before overwrite
    s_mux[0*AGPAD + t] = a0;
    s_mux[1*AGPAD + t] = a1;
    s_mux[2*AGPAD + t] = a2;
    s_mux[3*AGPAD + t] = a3;
  }
  __syncthreads();

  // stage 6: Y[d][c][k] = agg[c] @ Wot[k][:]  (float4 weight rows)
  {
    int cp = grp*2;
    const float* g0 = s_mux + cp*AGPAD;
    const float* g1 = s_mux + (cp+1)*AGPAD;
    const float4* wp = (const float4*)(Wot + k*256);
    float x0=0.f, x1=0.f;
    for(int u4=0; u4<64; u4++){
      float4 w4 = wp[u4];
      float4 a0 = *(const float4*)(g0 + u4*4);
      float4 a1 = *(const float4*)(g1 + u4*4);
      x0 += a0.x*w4.x + a0.y*w4.y + a0.z*w4.z + a0.w*w4.w;
      x1 += a1.x*w4.x + a1.y*w4.y + a1.z*w4.z + a1.w*w4.w;
    }
    Y[d*512 + cp*128 + k]     = x0;
    Y[d*512 + (cp+1)*128 + k] = x1;
  }
}

// ---------------- K5: per-node MLP chain, 4 nodes/block ------------
__global__ __launch_bounds__(256) void k_node(
    const float* __restrict__ rots, const float* __restrict__ trans,
    const float* __restrict__ Y,
    const float* __restrict__ Wg, const float* __restrict__ Wf1,
    const float* __restrict__ Wf2, const float* __restrict__ Wr1,
    const float* __restrict__ br1, const float* __restrict__ Wr2,
    const float* __restrict__ br2, const float* __restrict__ Wr3,
    const float* __restrict__ br3, const float* __restrict__ Wt,
    const int* __restrict__ nmask, float* __restrict__ out)
{
  __shared__ __align__(16) float s_y[4][4][128];
  __shared__ __align__(16) float s_t1[4][128];
  __shared__ __align__(16) float s_bb0[4][128];
  __shared__ __align__(16) float s_gv[4][3][128];
  __shared__ __align__(16) float s_h1[4][256];
  __shared__ __align__(16) float s_h2[4][128];
  __shared__ float s_sc[4][8];

  int b = blockIdx.x, t = threadIdx.x;
  int half = t >> 7, k = t & 127;
  int nb = half*2;
  int dbase = b*4;
  for(int i=t; i<4*512; i+=256){
    int nd = i>>9, c=(i>>7)&3, kk=i&127;
    s_y[nd][c][kk] = Y[(dbase+nd)*512 + c*128 + kk];
  }
  __syncthreads();

  float g[2]={0.f,0.f}, f1[2]={0.f,0.f};
  for(int j=0;j<128;j+=4){
    float wg0=Wg[(j+0)*128+k], wg1=Wg[(j+1)*128+k], wg2=Wg[(j+2)*128+k], wg3=Wg[(j+3)*128+k];
    float wf0=Wf1[(j+0)*128+k], wf1_=Wf1[(j+1)*128+k], wf2_=Wf1[(j+2)*128+k], wf3=Wf1[(j+3)*128+k];
#pragma unroll
    for(int nn=0;nn<2;nn++){
      float4 yv = *(const float4*)&s_y[nb+nn][0][j];
      g[nn]  += yv.x*wg0 + yv.y*wg1 + yv.z*wg2 + yv.w*wg3;
      f1[nn] += yv.x*wf0 + yv.y*wf1_ + yv.z*wf2_ + yv.w*wf3;
    }
  }
  float gate[2];
#pragma unroll
  for(int nn=0;nn<2;nn++){
    gate[nn] = 1.0f/(1.0f + expf(-g[nn]));
    s_t1[nb+nn][k] = fmaxf(f1[nn], 0.0f);
  }
  __syncthreads();

  float f0[2]={0.f,0.f};
  for(int j=0;j<128;j+=4){
    float w0=Wf2[(j+0)*128+k], w1=Wf2[(j+1)*128+k], w2=Wf2[(j+2)*128+k], w3=Wf2[(j+3)*128+k];
#pragma unroll
    for(int nn=0;nn<2;nn++){
      float4 tv = *(const float4*)&s_t1[nb+nn][j];
      f0[nn] += tv.x*w0 + tv.y*w1 + tv.z*w2 + tv.w*w3;
    }
  }
#pragma unroll
  for(int nn=0;nn<2;nn++){
    int d = dbase + nb + nn;
    float bb0 = s_y[nb+nn][0][k] + f0[nn];
    s_bb0[nb+nn][k] = bb0;
    out[OUT_BB + d*512 + k] = bb0;
#pragma unroll
    for(int c=1;c<4;c++){
      float v = s_y[nb+nn][c][k] * gate[nn];
      s_gv[nb+nn][c-1][k] = v;
      out[OUT_BB + d*512 + c*128 + k] = v;
    }
  }
  __syncthreads();

  float a1[2], a2[2];
  a1[0]=a1[1]=br1[k]; a2[0]=a2[1]=br1[128+k];
  for(int j=0;j<128;j+=4){
    float w10=Wr1[(j+0)*256+k],     w11=Wr1[(j+1)*256+k],     w12=Wr1[(j+2)*256+k],     w13=Wr1[(j+3)*256+k];
    float w20=Wr1[(j+0)*256+128+k], w21=Wr1[(j+1)*256+128+k], w22=Wr1[(j+2)*256+128+k], w23=Wr1[(j+3)*256+128+k];
#pragma unroll
    for(int nn=0;nn<2;nn++){
      float4 bv = *(const float4*)&s_bb0[nb+nn][j];
      a1[nn] += bv.x*w10 + bv.y*w11 + bv.z*w12 + bv.w*w13;
      a2[nn] += bv.x*w20 + bv.y*w21 + bv.z*w22 + bv.w*w23;
    }
  }
#pragma unroll
  for(int nn=0;nn<2;nn++){
    s_h1[nb+nn][k] = fmaxf(a1[nn], 0.0f);
    s_h1[nb+nn][128+k] = fmaxf(a2[nn], 0.0f);
  }
  __syncthreads();

  float a[2]; a[0]=a[1]=br2[k];
  for(int j=0;j<256;j+=4){
    float w0=Wr2[(j+0)*128+k], w1=Wr2[(j+1)*128+k], w2=Wr2[(j+2)*128+k], w3=Wr2[(j+3)*128+k];
#pragma unroll
    for(int nn=0;nn<2;nn++){
      float4 hv = *(const float4*)&s_h1[nb+nn][j];
      a[nn] += hv.x*w0 + hv.y*w1 + hv.z*w2 + hv.w*w3;
    }
  }
#pragma unroll
  for(int nn=0;nn<2;nn++) s_h2[nb+nn][k] = fmaxf(a[nn], 0.0f);
  __syncthreads();

  if(t < 12){
    int nd = t/3, r = t%3;
    float q = br3[r];
    for(int kk=0;kk<128;kk++) q += s_h2[nd][kk] * Wr3[kk*6 + r];
    s_sc[nd][r] = q;
  } else if(t >= 32 && t < 44){
    int q2 = t-32; int nd = q2/3, i = q2%3;
    float s = 0.f;
    for(int kk=0;kk<128;kk++) s += s_gv[nd][i][kk] * Wt[kk];
    s_sc[nd][4+i] = s;
  }
  __syncthreads();

  if(t < 4){
    int d = dbase + t;
    int nz = nmask[d];
    float q1=s_sc[t][0], q2=s_sc[t][1], q3=s_sc[t][2];
    float nrm = sqrtf(1.0f + q1*q1 + q2*q2 + q3*q3);
    float w=1.0f/nrm, x=q1/nrm, y=q2/nrm, z=q3/nrm;
    float Ru[3][3];
    Ru[0][0]=1.f-2.f*(y*y+z*z); Ru[0][1]=2.f*(x*y-w*z);     Ru[0][2]=2.f*(x*z+w*y);
    Ru[1][0]=2.f*(x*y+w*z);     Ru[1][1]=1.f-2.f*(x*x+z*z); Ru[1][2]=2.f*(y*z-w*x);
    Ru[2][0]=2.f*(x*z-w*y);     Ru[2][1]=2.f*(y*z+w*x);     Ru[2][2]=1.f-2.f*(x*x+y*y);
    for(int i=0;i<3;i++){
      for(int j=0;j<3;j++){
        float rv;
        if(nz){
          rv = rots[d*9+i*3+0]*Ru[0][j] + rots[d*9+i*3+1]*Ru[1][j] + rots[d*9+i*3+2]*Ru[2][j];
        } else {
          rv = rots[d*9+i*3+j];
        }
        out[OUT_ROT + d*9 + i*3 + j] = rv;
      }
      float tv = trans[d*3+i];
      out[OUT_TRANS + d*3 + i] = nz ? (tv + s_sc[t][4+i]) : tv;
    }
  }
}

extern "C" void kernel_launch(void* const* d_in, const int* in_sizes, int n_in,
                              void* d_out, int out_size, void* d_ws, size_t ws_size,
                              hipStream_t stream)
{
  (void)in_sizes; (void)n_in; (void)out_size; (void)ws_size;
  const float* rots = (const float*)d_in[0];
  const float* trans = (const float*)d_in[1];
  const float* nf   = (const float*)d_in[2];
  const float* Wa1  = (const float*)d_in[3];
  const float* ba1  = (const float*)d_in[4];
  const float* Wa2  = (const float*)d_in[5];
  const float* Wv   = (const float*)d_in[6];
  const float* Wo   = (const float*)d_in[7];
  const float* Wg   = (const float*)d_in[8];
  const float* Wf1  = (const float*)d_in[9];
  const float* Wf2  = (const float*)d_in[10];
  const float* Wr1  = (const float*)d_in[11];
  const float* br1  = (const float*)d_in[12];
  const float* Wr2  = (const float*)d_in[13];
  const float* br2  = (const float*)d_in[14];
  const float* Wr3  = (const float*)d_in[15];
  const float* br3  = (const float*)d_in[16];
  const float* Wt   = (const float*)d_in[17];
  const int* xmask  = (const int*)d_in[19];
  const int* nmask  = (const int*)d_in[20];

  float* P = (float*)d_ws;                 // NN*1024 f32  (8 MB), layout [n][u][c]
  float* U = P + NN*1024;                  // NN*128       (1 MB)
  float* V = U + NN*128;                   // NN*128       (1 MB)
  int* srcs = (int*)(V + NN*128);          // NN*40 int    (320 KB)
  float* Y  = (float*)(srcs + NN*NFIX);    // NN*512 f32   (4 MB)
  float* Trel = Y + NN*512;                // 1023*128 f32 (0.52 MB)
  float* Wot  = Trel + NREL*128;           // 128*256 f32  (128 KB)

  k_pretop<<<NN + 512 + 512 + 16, 256, 0, stream>>>(rots, trans, nf, Wa1, Wv, Wo,
                                                    xmask, nmask, P, U, V, srcs, Trel, Wot);
  k_attn<<<NN, 256, 0, stream>>>(trans, Wa1, ba1, Wa2, Wot, U, V, P, Trel, srcs, Y);
  k_node<<<NN/4, 256, 0, stream>>>(rots, trans, Y, Wg, Wf1, Wf2,
                                   Wr1, br1, Wr2, br2, Wr3, br3, Wt,
                                   nmask, (float*)d_out);
}

// Round 9
// 174.248 us; speedup vs baseline: 1.0165x; 1.0165x over previous
//
#include <hip/hip_runtime.h>
#include <hip/hip_bf16.h>
#include <math.h>

#define NN 2048
#define CHAIN 512
#define KNN 30
#define LRK 10
#define NFIX 40
#define NSLOT 42
#define HPAD 132
#define AGPAD 260
#define NREL 1023

#define OUT_ROT 0
#define OUT_TRANS (NN*9)
#define OUT_BB (NN*9 + NN*3)

#define THREEFRY_PARTITIONABLE 1

__device__ __forceinline__ int xcd_swz(int b){ return ((b & 7) << 8) | (b >> 3); }

// ---------------- threefry2x32, key = (0, 42) ----------------
__device__ __forceinline__ unsigned rotl32(unsigned x, unsigned r){ return (x<<r)|(x>>(32u-r)); }

__device__ __forceinline__ void tf_block(unsigned &x0, unsigned &x1){
  const unsigned k0 = 0u, k1 = 42u, k2 = 0x1BD11BDAu ^ 0u ^ 42u;
  x0 += k0; x1 += k1;
#define TFR(a) x0 += x1; x1 = rotl32(x1,(a)); x1 ^= x0;
  TFR(13) TFR(15) TFR(26) TFR(6)   x0 += k1; x1 += k2 + 1u;
  TFR(17) TFR(29) TFR(16) TFR(24)  x0 += k2; x1 += k0 + 2u;
  TFR(13) TFR(15) TFR(26) TFR(6)   x0 += k0; x1 += k1 + 3u;
  TFR(17) TFR(29) TFR(16) TFR(24)  x0 += k1; x1 += k2 + 4u;
  TFR(13) TFR(15) TFR(26) TFR(6)   x0 += k2; x1 += k0 + 5u;
#undef TFR
}

__device__ __forceinline__ float gumbel_from_bits(unsigned bits){
  float f = __uint_as_float((bits >> 9) | 0x3f800000u) - 1.0f;
  const float tiny = 1.17549435e-38f;
  float u = fmaxf(tiny, f * (1.0f - tiny) + tiny);
  return -logf(-logf(u));
}

__device__ __forceinline__ float gumbel_at(unsigned p){
#if THREEFRY_PARTITIONABLE
  unsigned x0 = 0u, x1 = p;
  tf_block(x0, x1);
  return gumbel_from_bits(x0 ^ x1);
#else
  const unsigned HALF = (NN*(unsigned)NN)/2u;
  unsigned c0, c1; bool lo = p < HALF;
  if(lo){ c0 = p; c1 = p + HALF; } else { c0 = p - HALF; c1 = p; }
  tf_block(c0, c1);
  return gumbel_from_bits(lo ? c0 : c1);
#endif
}

// ---------------- K1: fused topk / prep / Trel / Wot (block-role split) ------------
__global__ __launch_bounds__(256) void k_pretop(
    const float* __restrict__ rots, const float* __restrict__ trans,
    const float* __restrict__ nf, const float* __restrict__ Wa1,
    const float* __restrict__ Wv, const float* __restrict__ Wo,
    const int* __restrict__ xmask, const int* __restrict__ nmask,
    float* __restrict__ P, float* __restrict__ U, float* __restrict__ V,
    int* __restrict__ srcs, float* __restrict__ Trel, float* __restrict__ Wot)
{
  __shared__ __align__(16) char smem[4*4*132*4];
  int bb = blockIdx.x, t = threadIdx.x;

  if(bb >= NN + 1024){
    // ---------------- Wot role: Wot[k][u] = Wo[u][k] ----------------
    int b2 = bb - (NN + 1024);        // 0..15
    int i0 = b2*8192;
    for(int i = i0 + t; i < i0 + 8192; i += 256){
      int kk2 = i >> 8, uu = i & 255;
      Wot[i] = Wo[uu*128 + kk2];
    }
    return;
  }

  if(bb >= NN + 512){
    // ---------------- Trel role ----------------
    int r = (bb - (NN+512))*2 + (t >> 7);
    int k = t & 127;
    if(r < NREL){
      float rel = (float)(r - 511);
      float acc = 0.f;
#pragma unroll
      for(int j=0;j<8;j++){
        float fr = expf((float)(2*j) * (float)(-0.5756462732485115));
        float ang = rel * fr;
        acc += cosf(ang) * Wa1[(278+j)*128 + k];
        acc += sinf(ang) * Wa1[(286+j)*128 + k];
      }
      Trel[r*128 + k] = acc;
    }
    return;
  }

  if(bb < NN){
    // ---------------- topk role ----------------
    unsigned* s_kk = (unsigned*)smem;          // [512]
    unsigned* s_lk = s_kk + CHAIN;             // [512]
    int i = bb;
    int base = (i >> 9) << 9;
    float tx = trans[i*3+0], ty = trans[i*3+1], tz = trans[i*3+2];
    for(int q=t; q<CHAIN; q+=256){
      int j = base + q;
      float dx = __fsub_rn(trans[j*3+0], tx);
      float dy = __fsub_rn(trans[j*3+1], ty);
      float dz = __fsub_rn(trans[j*3+2], tz);
      float d2 = __fadd_rn(__fadd_rn(__fmul_rn(dx,dx),__fmul_rn(dy,dy)),__fmul_rn(dz,dz));
      bool val = (j != i);
      float dm = val ? d2 : 1e30f;
      s_kk[q] = __float_as_uint(dm) ^ 0x80000000u;
      if(val){
        float g = gumbel_at((unsigned)(i*NN + j));
        float sc = __fadd_rn(__fmul_rn(-1.5f, logf(dm)), g);
        unsigned b = __float_as_uint(sc);
        unsigned ord = b ^ ((b & 0x80000000u) ? 0xFFFFFFFFu : 0x80000000u);
        s_lk[q] = ~ord;
      } else {
        s_lk[q] = 0xFFFFFFFFu;
      }
    }
    __syncthreads();
    if(t < 128){
      int w = t >> 6, lane = t & 63;
      unsigned* arr = w ? s_lk : s_kk;
      int K = w ? LRK : KNN;
      int outoff = w ? KNN : 0;
      unsigned long long best = ~0ull;
      for(int q=lane; q<CHAIN; q+=64){
        unsigned long long kk = ((unsigned long long)arr[q]<<32) | (unsigned)q;
        if(kk < best) best = kk;
      }
      for(int k=0;k<K;k++){
        unsigned long long r = best;
        for(int off=32; off; off>>=1){
          unsigned long long o = __shfl_xor(r, off, 64);
          if(o < r) r = o;
        }
        int winq = (int)(unsigned)(r & 0xffffffffull);
        if(lane == 0){
          srcs[i*NFIX + outoff + k] = base + winq;
          arr[winq] = 0xFFFFFFFFu;
        }
        asm volatile("s_waitcnt lgkmcnt(0)" ::: "memory");
        __builtin_amdgcn_wave_barrier();
        if((winq & 63) == lane){
          best = ~0ull;
          for(int q=lane; q<CHAIN; q+=64){
            unsigned long long kk = ((unsigned long long)arr[q]<<32) | (unsigned)q;
            if(kk < best) best = kk;
          }
        }
      }
    }
    return;
  }

  // ---------------- prep role (4 nodes) ----------------
  float (*fr)[4][132] = (float (*)[4][132])smem;
  int n0 = (bb - NN)*4;
  for(int i=t; i<2048; i+=256){
    int nd = i>>9, c = (i>>7)&3, kk = i&127;
    fr[nd][c][kk] = nf[(n0+nd)*512 + c*128 + kk];
  }
  if(t < 4){
    fr[t][0][128] = 0.0f; fr[t][0][129] = 0.0f;
    fr[t][0][130] = (nmask[n0+t] != 0 && xmask[n0+t] == 0) ? 1.0f : 0.0f;
  } else if(t >= 16 && t < 52){
    int q = t - 16; int nd = q/9, r = q%9, a = r/3, i = r%3;
    int n = n0 + nd;
    const float BB[3][3] = {{-0.525f,1.363f,0.0f},{0.f,0.f,0.f},{1.526f,0.f,0.f}};
    float bb_ = rots[n*9+i*3+0]*BB[a][0] + rots[n*9+i*3+1]*BB[a][1]
              + rots[n*9+i*3+2]*BB[a][2] + trans[n*3+i];
    fr[nd][1+i][128+a] = bb_;
  }
  __syncthreads();

  float a[4][4];
#pragma unroll
  for(int nd=0;nd<4;nd++)
#pragma unroll
    for(int c=0;c<4;c++) a[nd][c]=0.f;
  for(int j=0;j<128;j+=4){
    float w0=Wv[(j+0)*256+t], w1=Wv[(j+1)*256+t], w2=Wv[(j+2)*256+t], w3=Wv[(j+3)*256+t];
#pragma unroll
    for(int nd=0;nd<4;nd++){
#pragma unroll
      for(int c=0;c<4;c++){
        float4 f4 = *(const float4*)&fr[nd][c][j];
        a[nd][c] += f4.x*w0 + f4.y*w1 + f4.z*w2 + f4.w*w3;
      }
    }
  }
  for(int j=128;j<131;j++){
    float w = Wv[j*256+t];
#pragma unroll
    for(int nd=0;nd<4;nd++)
#pragma unroll
      for(int c=0;c<4;c++) a[nd][c] += fr[nd][c][j]*w;
  }
#pragma unroll
  for(int nd=0;nd<4;nd++){
    float4 v4; v4.x=a[nd][0]; v4.y=a[nd][1]; v4.z=a[nd][2]; v4.w=a[nd][3];
    *(float4*)&P[(n0+nd)*1024 + t*4] = v4;   // layout [n][u][c]
  }

  int k = t & 127;
  int isV = t >> 7;
  const float* Wcol = Wa1 + (isV ? 131*128 : 0);
  float u[4] = {0.f,0.f,0.f,0.f};
  for(int j=0;j<128;j+=4){
    float w0=Wcol[(j+0)*128+k], w1=Wcol[(j+1)*128+k], w2=Wcol[(j+2)*128+k], w3=Wcol[(j+3)*128+k];
#pragma unroll
    for(int nd=0;nd<4;nd++){
      float4 f4 = *(const float4*)&fr[nd][0][j];
      u[nd] += f4.x*w0 + f4.y*w1 + f4.z*w2 + f4.w*w3;
    }
  }
  for(int j=128;j<131;j++){
    float w = Wcol[j*128+k];
#pragma unroll
    for(int nd=0;nd<4;nd++) u[nd] += fr[nd][0][j]*w;
  }
  float* OUT = isV ? V : U;
#pragma unroll
  for(int nd=0;nd<4;nd++) OUT[(n0+nd)*128 + k] = u[nd];
}

// ---------------- K3: edge logits + softmax + agg + @Wot (fused, R7 structure) ----
__global__ __launch_bounds__(256) void k_attn(
    const float* __restrict__ trans, const float* __restrict__ Wa1,
    const float* __restrict__ ba1, const float* __restrict__ Wa2,
    const float* __restrict__ Wot,
    const float* __restrict__ U, const float* __restrict__ V,
    const float* __restrict__ P, const float* __restrict__ Trel,
    const int* __restrict__ srcs, float* __restrict__ Y)
{
  __shared__ int   s_src[NSLOT];
  __shared__ int   s_val[NSLOT];
  __shared__ float s_dist[NSLOT];
  __shared__ __align__(16) float s_H[NSLOT*HPAD];   // 22176 B
  __shared__ __align__(16) float s_mux[NSLOT*32];   // 5376 B: rbf(42*16) | wa2t(8*132) | agg(4*260)
  __shared__ float s_att[NSLOT*8];

  int b = blockIdx.x, t = threadIdx.x;
  int d = xcd_swz(b);
  int pos = d & (CHAIN-1);
  int k = t & 127, grp = t >> 7;

  // stage 0: edge meta
  if(t < NSLOT){
    int src;
    if(t < NFIX)      src = srcs[d*NFIX + t];
    else if(t == NFIX) src = (pos > 0)       ? d-1 : d;
    else               src = (pos < CHAIN-1) ? d+1 : d;
    s_src[t] = src;
    float dx = trans[src*3+0]-trans[d*3+0];
    float dy = trans[src*3+1]-trans[d*3+1];
    float dz = trans[src*3+2]-trans[d*3+2];
    float dist = sqrtf(dx*dx + dy*dy + dz*dz + 1e-12f);
    s_dist[t] = dist;
    s_val[t] = (dist > 1e-3f) ? 1 : 0;
  }

  // per-thread rbf weight column (16 floats -> stays in VGPRs)
  float wreg[16];
#pragma unroll
  for(int f=0; f<16; f++) wreg[f] = Wa1[(262+f)*128 + k];
  float ubias = ba1[k] + V[d*128 + k];
  __syncthreads();

  // stage 1: rbf[42][16]
  for(int i=t; i<NSLOT*16; i+=256){
    int e = i >> 4, f = i & 15;
    float zz = (s_dist[e] - (float)f * (20.0f/15.0f)) * 0.8f;
    s_mux[i] = expf(-(zz*zz));
  }
  __syncthreads();

  // stage 2: H[e][k] = leaky(U[src][k] + Trel[src-d+511][k] + ubias + rbf[e].wreg)
  for(int e = grp; e < NSLOT; e += 2){
    int src = s_src[e];
    float h = ubias + U[src*128 + k] + Trel[(src - d + 511)*128 + k];
    const float4* rp = (const float4*)(s_mux + e*16);
#pragma unroll
    for(int q=0; q<4; q++){
      float4 ev = rp[q];
      h += ev.x*wreg[4*q+0] + ev.y*wreg[4*q+1] + ev.z*wreg[4*q+2] + ev.w*wreg[4*q+3];
    }
    h = (h >= 0.0f) ? h : 0.01f*h;
    s_H[e*HPAD + k] = h;
  }
  __syncthreads();

  // stage 2.5: Wa2^T -> s_mux (rbf dead)
  for(int i=t; i<1024; i+=256){
    int kk = i >> 3, h = i & 7;
    s_mux[h*HPAD + kk] = Wa2[i];
  }
  __syncthreads();

  // stage 3: logits[e][h] = H[e] . Wa2[:,h]  (336 parallel float4 dots)
  for(int p = t; p < NSLOT*8; p += 256){
    int e = p >> 3, h = p & 7;
    const float4* Hp = (const float4*)(s_H + e*HPAD);
    const float4* Wp = (const float4*)(s_mux + h*HPAD);
    float acc = 0.f;
#pragma unroll
    for(int q=0; q<32; q++){
      float4 a = Hp[q], w = Wp[q];
      acc += a.x*w.x + a.y*w.y + a.z*w.z + a.w*w.w;
    }
    s_att[p] = s_val[e] ? acc : -1e30f;
  }
  __syncthreads();

  // stage 4: per-head softmax
  if(t < 64){
    int h = t & 7, g = t >> 3;
    float m = -INFINITY;
    for(int e=g; e<NSLOT; e+=8) m = fmaxf(m, s_att[e*8+h]);
    for(int off=8; off<64; off<<=1) m = fmaxf(m, __shfl_xor(m, off, 64));
    m = (m > -5e29f) ? m : 0.0f;
    float z = 0.0f;
    for(int e=g; e<NSLOT; e+=8){
      float p = expf(s_att[e*8+h] - m);
      s_att[e*8+h] = p; z += p;
    }
    for(int off=8; off<64; off<<=1) z += __shfl_xor(z, off, 64);
    float inv = 1.0f / (z + 1e-9f);
    for(int e=g; e<NSLOT; e+=8) s_att[e*8+h] *= inv;
  }
  __syncthreads();

  // stage 5: agg[u=t][c] = sum_e attn[e][u>>5] * P[src][u][c], 1-deep pipelined
  {
    int h = t >> 5;
    float a0=0.f,a1=0.f,a2=0.f,a3=0.f;
    float4 pn = *(const float4*)(P + (size_t)s_src[0]*1024 + t*4);
    float wn = s_att[h];
    for(int e=0;e<NSLOT;e++){
      float4 pc = pn; float wc = wn;
      if(e+1 < NSLOT){
        pn = *(const float4*)(P + (size_t)s_src[e+1]*1024 + t*4);
        wn = s_att[(e+1)*8 + h];
      }
      a0 += wc*pc.x; a1 += wc*pc.y; a2 += wc*pc.z; a3 += wc*pc.w;
    }
    __syncthreads();   // s_mux (wa2t) readers done before overwrite with agg
    s_mux[0*AGPAD + t] = a0;
    s_mux[1*AGPAD + t] = a1;
    s_mux[2*AGPAD + t] = a2;
    s_mux[3*AGPAD + t] = a3;
  }
  __syncthreads();

  // stage 6: Y[d][c][k] = agg[c] @ Wot[k][:]  (float4 weight rows)
  {
    int cp = grp*2;
    const float* g0 = s_mux + cp*AGPAD;
    const float* g1 = s_mux + (cp+1)*AGPAD;
    const float4* wp = (const float4*)(Wot + k*256);
    float x0=0.f, x1=0.f;
    for(int u4=0; u4<64; u4++){
      float4 w4 = wp[u4];
      float4 a0 = *(const float4*)(g0 + u4*4);
      float4 a1 = *(const float4*)(g1 + u4*4);
      x0 += a0.x*w4.x + a0.y*w4.y + a0.z*w4.z + a0.w*w4.w;
      x1 += a1.x*w4.x + a1.y*w4.y + a1.z*w4.z + a1.w*w4.w;
    }
    Y[d*512 + cp*128 + k]     = x0;
    Y[d*512 + (cp+1)*128 + k] = x1;
  }
}

// ---------------- K5: per-node MLP chain, 4 nodes/block ------------
__global__ __launch_bounds__(256) void k_node(
    const float* __restrict__ rots, const float* __restrict__ trans,
    const float* __restrict__ Y,
    const float* __restrict__ Wg, const float* __restrict__ Wf1,
    const float* __restrict__ Wf2, const float* __restrict__ Wr1,
    const float* __restrict__ br1, const float* __restrict__ Wr2,
    const float* __restrict__ br2, const float* __restrict__ Wr3,
    const float* __restrict__ br3, const float* __restrict__ Wt,
    const int* __restrict__ nmask, float* __restrict__ out)
{
  __shared__ __align__(16) float s_y[4][4][128];
  __shared__ __align__(16) float s_t1[4][128];
  __shared__ __align__(16) float s_bb0[4][128];
  __shared__ __align__(16) float s_gv[4][3][128];
  __shared__ __align__(16) float s_h1[4][256];
  __shared__ __align__(16) float s_h2[4][128];
  __shared__ float s_sc[4][8];

  int b = blockIdx.x, t = threadIdx.x;
  int half = t >> 7, k = t & 127;
  int nb = half*2;
  int dbase = b*4;
  for(int i=t; i<4*512; i+=256){
    int nd = i>>9, c=(i>>7)&3, kk=i&127;
    s_y[nd][c][kk] = Y[(dbase+nd)*512 + c*128 + kk];
  }
  __syncthreads();

  float g[2]={0.f,0.f}, f1[2]={0.f,0.f};
  for(int j=0;j<128;j+=4){
    float wg0=Wg[(j+0)*128+k], wg1=Wg[(j+1)*128+k], wg2=Wg[(j+2)*128+k], wg3=Wg[(j+3)*128+k];
    float wf0=Wf1[(j+0)*128+k], wf1_=Wf1[(j+1)*128+k], wf2_=Wf1[(j+2)*128+k], wf3=Wf1[(j+3)*128+k];
#pragma unroll
    for(int nn=0;nn<2;nn++){
      float4 yv = *(const float4*)&s_y[nb+nn][0][j];
      g[nn]  += yv.x*wg0 + yv.y*wg1 + yv.z*wg2 + yv.w*wg3;
      f1[nn] += yv.x*wf0 + yv.y*wf1_ + yv.z*wf2_ + yv.w*wf3;
    }
  }
  float gate[2];
#pragma unroll
  for(int nn=0;nn<2;nn++){
    gate[nn] = 1.0f/(1.0f + expf(-g[nn]));
    s_t1[nb+nn][k] = fmaxf(f1[nn], 0.0f);
  }
  __syncthreads();

  float f0[2]={0.f,0.f};
  for(int j=0;j<128;j+=4){
    float w0=Wf2[(j+0)*128+k], w1=Wf2[(j+1)*128+k], w2=Wf2[(j+2)*128+k], w3=Wf2[(j+3)*128+k];
#pragma unroll
    for(int nn=0;nn<2;nn++){
      float4 tv = *(const float4*)&s_t1[nb+nn][j];
      f0[nn] += tv.x*w0 + tv.y*w1 + tv.z*w2 + tv.w*w3;
    }
  }
#pragma unroll
  for(int nn=0;nn<2;nn++){
    int d = dbase + nb + nn;
    float bb0 = s_y[nb+nn][0][k] + f0[nn];
    s_bb0[nb+nn][k] = bb0;
    out[OUT_BB + d*512 + k] = bb0;
#pragma unroll
    for(int c=1;c<4;c++){
      float v = s_y[nb+nn][c][k] * gate[nn];
      s_gv[nb+nn][c-1][k] = v;
      out[OUT_BB + d*512 + c*128 + k] = v;
    }
  }
  __syncthreads();

  float a1[2], a2[2];
  a1[0]=a1[1]=br1[k]; a2[0]=a2[1]=br1[128+k];
  for(int j=0;j<128;j+=4){
    float w10=Wr1[(j+0)*256+k],     w11=Wr1[(j+1)*256+k],     w12=Wr1[(j+2)*256+k],     w13=Wr1[(j+3)*256+k];
    float w20=Wr1[(j+0)*256+128+k], w21=Wr1[(j+1)*256+128+k], w22=Wr1[(j+2)*256+128+k], w23=Wr1[(j+3)*256+128+k];
#pragma unroll
    for(int nn=0;nn<2;nn++){
      float4 bv = *(const float4*)&s_bb0[nb+nn][j];
      a1[nn] += bv.x*w10 + bv.y*w11 + bv.z*w12 + bv.w*w13;
      a2[nn] += bv.x*w20 + bv.y*w21 + bv.z*w22 + bv.w*w23;
    }
  }
#pragma unroll
  for(int nn=0;nn<2;nn++){
    s_h1[nb+nn][k] = fmaxf(a1[nn], 0.0f);
    s_h1[nb+nn][128+k] = fmaxf(a2[nn], 0.0f);
  }
  __syncthreads();

  float a[2]; a[0]=a[1]=br2[k];
  for(int j=0;j<256;j+=4){
    float w0=Wr2[(j+0)*128+k], w1=Wr2[(j+1)*128+k], w2=Wr2[(j+2)*128+k], w3=Wr2[(j+3)*128+k];
#pragma unroll
    for(int nn=0;nn<2;nn++){
      float4 hv = *(const float4*)&s_h1[nb+nn][j];
      a[nn] += hv.x*w0 + hv.y*w1 + hv.z*w2 + hv.w*w3;
    }
  }
#pragma unroll
  for(int nn=0;nn<2;nn++) s_h2[nb+nn][k] = fmaxf(a[nn], 0.0f);
  __syncthreads();

  if(t < 12){
    int nd = t/3, r = t%3;
    float q = br3[r];
    for(int kk=0;kk<128;kk++) q += s_h2[nd][kk] * Wr3[kk*6 + r];
    s_sc[nd][r] = q;
  } else if(t >= 32 && t < 44){
    int q2 = t-32; int nd = q2/3, i = q2%3;
    float s = 0.f;
    for(int kk=0;kk<128;kk++) s += s_gv[nd][i][kk] * Wt[kk];
    s_sc[nd][4+i] = s;
  }
  __syncthreads();

  if(t < 4){
    int d = dbase + t;
    int nz = nmask[d];
    float q1=s_sc[t][0], q2=s_sc[t][1], q3=s_sc[t][2];
    float nrm = sqrtf(1.0f + q1*q1 + q2*q2 + q3*q3);
    float w=1.0f/nrm, x=q1/nrm, y=q2/nrm, z=q3/nrm;
    float Ru[3][3];
    Ru[0][0]=1.f-2.f*(y*y+z*z); Ru[0][1]=2.f*(x*y-w*z);     Ru[0][2]=2.f*(x*z+w*y);
    Ru[1][0]=2.f*(x*y+w*z);     Ru[1][1]=1.f-2.f*(x*x+z*z); Ru[1][2]=2.f*(y*z-w*x);
    Ru[2][0]=2.f*(x*z-w*y);     Ru[2][1]=2.f*(y*z+w*x);     Ru[2][2]=1.f-2.f*(x*x+y*y);
    for(int i=0;i<3;i++){
      for(int j=0;j<3;j++){
        float rv;
        if(nz){
          rv = rots[d*9+i*3+0]*Ru[0][j] + rots[d*9+i*3+1]*Ru[1][j] + rots[d*9+i*3+2]*Ru[2][j];
        } else {
          rv = rots[d*9+i*3+j];
        }
        out[OUT_ROT + d*9 + i*3 + j] = rv;
      }
      float tv = trans[d*3+i];
      out[OUT_TRANS + d*3 + i] = nz ? (tv + s_sc[t][4+i]) : tv;
    }
  }
}

extern "C" void kernel_launch(void* const* d_in, const int* in_sizes, int n_in,
                              void* d_out, int out_size, void* d_ws, size_t ws_size,
                              hipStream_t stream)
{
  (void)in_sizes; (void)n_in; (void)out_size; (void)ws_size;
  const float* rots = (const float*)d_in[0];
  const float* trans = (const float*)d_in[1];
  const float* nf   = (const float*)d_in[2];
  const float* Wa1  = (const float*)d_in[3];
  const float* ba1  = (const float*)d_in[4];
  const float* Wa2  = (const float*)d_in[5];
  const float* Wv   = (const float*)d_in[6];
  const float* Wo   = (const float*)d_in[7];
  const float* Wg   = (const float*)d_in[8];
  const float* Wf1  = (const float*)d_in[9];
  const float* Wf2  = (const float*)d_in[10];
  const float* Wr1  = (const float*)d_in[11];
  const float* br1  = (const float*)d_in[12];
  const float* Wr2  = (const float*)d_in[13];
  const float* br2  = (const float*)d_in[14];
  const float* Wr3  = (const float*)d_in[15];
  const float* br3  = (const float*)d_in[16];
  const float* Wt   = (const float*)d_in[17];
  const int* xmask  = (const int*)d_in[19];
  const int* nmask  = (const int*)d_in[20];

  float* P = (float*)d_ws;                 // NN*1024 f32  (8 MB), layout [n][u][c]
  float* U = P + NN*1024;                  // NN*128       (1 MB)
  float* V = U + NN*128;                   // NN*128       (1 MB)
  int* srcs = (int*)(V + NN*128);          // NN*40 int    (320 KB)
  float* Y  = (float*)(srcs + NN*NFIX);    // NN*512 f32   (4 MB)
  float* Trel = Y + NN*512;                // 1023*128 f32 (0.52 MB)
  float* Wot  = Trel + NREL*128;           // 128*256 f32  (128 KB)

  k_pretop<<<NN + 512 + 512 + 16, 256, 0, stream>>>(rots, trans, nf, Wa1, Wv, Wo,
                                                    xmask, nmask, P, U, V, srcs, Trel, Wot);
  k_attn<<<NN, 256, 0, stream>>>(trans, Wa1, ba1, Wa2, Wot, U, V, P, Trel, srcs, Y);
  k_node<<<NN/4, 256, 0, stream>>>(rots, trans, Y, Wg, Wf1, Wf2,
                                   Wr1, br1, Wr2, br2, Wr3, br3, Wt,
                                   nmask, (float*)d_out);
}

// Round 10
// 142.327 us; speedup vs baseline: 1.2445x; 1.2243x over previous
//
#include <hip/hip_runtime.h>
#include <hip/hip_bf16.h>
#include <math.h>

#define NN 2048
#define CHAIN 512
#define KNN 30
#define LRK 10
#define NFIX 40
#define NSLOT 42
#define HPAD 132
#define AGPAD 260
#define NREL 1023

#define OUT_ROT 0
#define OUT_TRANS (NN*9)
#define OUT_BB (NN*9 + NN*3)

#define THREEFRY_PARTITIONABLE 1

__device__ __forceinline__ int xcd_swz(int b){ return ((b & 7) << 8) | (b >> 3); }

// ---------------- threefry2x32, key = (0, 42) ----------------
__device__ __forceinline__ unsigned rotl32(unsigned x, unsigned r){ return (x<<r)|(x>>(32u-r)); }

__device__ __forceinline__ void tf_block(unsigned &x0, unsigned &x1){
  const unsigned k0 = 0u, k1 = 42u, k2 = 0x1BD11BDAu ^ 0u ^ 42u;
  x0 += k0; x1 += k1;
#define TFR(a) x0 += x1; x1 = rotl32(x1,(a)); x1 ^= x0;
  TFR(13) TFR(15) TFR(26) TFR(6)   x0 += k1; x1 += k2 + 1u;
  TFR(17) TFR(29) TFR(16) TFR(24)  x0 += k2; x1 += k0 + 2u;
  TFR(13) TFR(15) TFR(26) TFR(6)   x0 += k0; x1 += k1 + 3u;
  TFR(17) TFR(29) TFR(16) TFR(24)  x0 += k1; x1 += k2 + 4u;
  TFR(13) TFR(15) TFR(26) TFR(6)   x0 += k2; x1 += k0 + 5u;
#undef TFR
}

__device__ __forceinline__ float gumbel_from_bits(unsigned bits){
  float f = __uint_as_float((bits >> 9) | 0x3f800000u) - 1.0f;
  const float tiny = 1.17549435e-38f;
  float u = fmaxf(tiny, f * (1.0f - tiny) + tiny);
  return -logf(-logf(u));
}

__device__ __forceinline__ float gumbel_at(unsigned p){
#if THREEFRY_PARTITIONABLE
  unsigned x0 = 0u, x1 = p;
  tf_block(x0, x1);
  return gumbel_from_bits(x0 ^ x1);
#else
  const unsigned HALF = (NN*(unsigned)NN)/2u;
  unsigned c0, c1; bool lo = p < HALF;
  if(lo){ c0 = p; c1 = p + HALF; } else { c0 = p - HALF; c1 = p; }
  tf_block(c0, c1);
  return gumbel_from_bits(lo ? c0 : c1);
#endif
}

// ---------------- K1: fused topk / prep / Trel (block-role split) ------------
__global__ __launch_bounds__(256) void k_pretop(
    const float* __restrict__ rots, const float* __restrict__ trans,
    const float* __restrict__ nf, const float* __restrict__ Wa1,
    const float* __restrict__ Wv,
    const int* __restrict__ xmask, const int* __restrict__ nmask,
    float* __restrict__ P, float* __restrict__ U, float* __restrict__ V,
    int* __restrict__ srcs, float* __restrict__ Trel)
{
  __shared__ __align__(16) char smem[4*4*132*4];
  int bb = blockIdx.x, t = threadIdx.x;

  if(bb >= NN + 512){
    // ---------------- Trel role ----------------
    int r = (bb - (NN+512))*2 + (t >> 7);
    int k = t & 127;
    if(r < NREL){
      float rel = (float)(r - 511);
      float acc = 0.f;
#pragma unroll
      for(int j=0;j<8;j++){
        float fr = expf((float)(2*j) * (float)(-0.5756462732485115));
        float ang = rel * fr;
        acc += cosf(ang) * Wa1[(278+j)*128 + k];
        acc += sinf(ang) * Wa1[(286+j)*128 + k];
      }
      Trel[r*128 + k] = acc;
    }
    return;
  }

  if(bb < NN){
    // ---------------- topk role ----------------
    unsigned* s_kk = (unsigned*)smem;          // [512]
    unsigned* s_lk = s_kk + CHAIN;             // [512]
    int i = bb;
    int base = (i >> 9) << 9;
    float tx = trans[i*3+0], ty = trans[i*3+1], tz = trans[i*3+2];
    for(int q=t; q<CHAIN; q+=256){
      int j = base + q;
      float dx = __fsub_rn(trans[j*3+0], tx);
      float dy = __fsub_rn(trans[j*3+1], ty);
      float dz = __fsub_rn(trans[j*3+2], tz);
      float d2 = __fadd_rn(__fadd_rn(__fmul_rn(dx,dx),__fmul_rn(dy,dy)),__fmul_rn(dz,dz));
      bool val = (j != i);
      float dm = val ? d2 : 1e30f;
      s_kk[q] = __float_as_uint(dm) ^ 0x80000000u;
      if(val){
        float g = gumbel_at((unsigned)(i*NN + j));
        float sc = __fadd_rn(__fmul_rn(-1.5f, logf(dm)), g);
        unsigned b = __float_as_uint(sc);
        unsigned ord = b ^ ((b & 0x80000000u) ? 0xFFFFFFFFu : 0x80000000u);
        s_lk[q] = ~ord;
      } else {
        s_lk[q] = 0xFFFFFFFFu;
      }
    }
    __syncthreads();
    if(t < 128){
      int w = t >> 6, lane = t & 63;
      unsigned* arr = w ? s_lk : s_kk;
      int K = w ? LRK : KNN;
      int outoff = w ? KNN : 0;
      unsigned long long best = ~0ull;
      for(int q=lane; q<CHAIN; q+=64){
        unsigned long long kk = ((unsigned long long)arr[q]<<32) | (unsigned)q;
        if(kk < best) best = kk;
      }
      for(int k=0;k<K;k++){
        unsigned long long r = best;
        for(int off=32; off; off>>=1){
          unsigned long long o = __shfl_xor(r, off, 64);
          if(o < r) r = o;
        }
        int winq = (int)(unsigned)(r & 0xffffffffull);
        if(lane == 0){
          srcs[i*NFIX + outoff + k] = base + winq;
          arr[winq] = 0xFFFFFFFFu;
        }
        asm volatile("s_waitcnt lgkmcnt(0)" ::: "memory");
        __builtin_amdgcn_wave_barrier();
        if((winq & 63) == lane){
          best = ~0ull;
          for(int q=lane; q<CHAIN; q+=64){
            unsigned long long kk = ((unsigned long long)arr[q]<<32) | (unsigned)q;
            if(kk < best) best = kk;
          }
        }
      }
    }
    return;
  }

  // ---------------- prep role (4 nodes) ----------------
  float (*fr)[4][132] = (float (*)[4][132])smem;
  int n0 = (bb - NN)*4;
  for(int i=t; i<2048; i+=256){
    int nd = i>>9, c = (i>>7)&3, kk = i&127;
    fr[nd][c][kk] = nf[(n0+nd)*512 + c*128 + kk];
  }
  if(t < 4){
    fr[t][0][128] = 0.0f; fr[t][0][129] = 0.0f;
    fr[t][0][130] = (nmask[n0+t] != 0 && xmask[n0+t] == 0) ? 1.0f : 0.0f;
  } else if(t >= 16 && t < 52){
    int q = t - 16; int nd = q/9, r = q%9, a = r/3, i = r%3;
    int n = n0 + nd;
    const float BB[3][3] = {{-0.525f,1.363f,0.0f},{0.f,0.f,0.f},{1.526f,0.f,0.f}};
    float bb_ = rots[n*9+i*3+0]*BB[a][0] + rots[n*9+i*3+1]*BB[a][1]
              + rots[n*9+i*3+2]*BB[a][2] + trans[n*3+i];
    fr[nd][1+i][128+a] = bb_;
  }
  __syncthreads();

  float a[4][4];
#pragma unroll
  for(int nd=0;nd<4;nd++)
#pragma unroll
    for(int c=0;c<4;c++) a[nd][c]=0.f;
  for(int j=0;j<128;j+=4){
    float w0=Wv[(j+0)*256+t], w1=Wv[(j+1)*256+t], w2=Wv[(j+2)*256+t], w3=Wv[(j+3)*256+t];
#pragma unroll
    for(int nd=0;nd<4;nd++){
#pragma unroll
      for(int c=0;c<4;c++){
        float4 f4 = *(const float4*)&fr[nd][c][j];
        a[nd][c] += f4.x*w0 + f4.y*w1 + f4.z*w2 + f4.w*w3;
      }
    }
  }
  for(int j=128;j<131;j++){
    float w = Wv[j*256+t];
#pragma unroll
    for(int nd=0;nd<4;nd++)
#pragma unroll
      for(int c=0;c<4;c++) a[nd][c] += fr[nd][c][j]*w;
  }
#pragma unroll
  for(int nd=0;nd<4;nd++){
    float4 v4; v4.x=a[nd][0]; v4.y=a[nd][1]; v4.z=a[nd][2]; v4.w=a[nd][3];
    *(float4*)&P[(n0+nd)*1024 + t*4] = v4;   // layout [n][u][c]
  }

  int k = t & 127;
  int isV = t >> 7;
  const float* Wcol = Wa1 + (isV ? 131*128 : 0);
  float u[4] = {0.f,0.f,0.f,0.f};
  for(int j=0;j<128;j+=4){
    float w0=Wcol[(j+0)*128+k], w1=Wcol[(j+1)*128+k], w2=Wcol[(j+2)*128+k], w3=Wcol[(j+3)*128+k];
#pragma unroll
    for(int nd=0;nd<4;nd++){
      float4 f4 = *(const float4*)&fr[nd][0][j];
      u[nd] += f4.x*w0 + f4.y*w1 + f4.z*w2 + f4.w*w3;
    }
  }
  for(int j=128;j<131;j++){
    float w = Wcol[j*128+k];
#pragma unroll
    for(int nd=0;nd<4;nd++) u[nd] += fr[nd][0][j]*w;
  }
  float* OUT = isV ? V : U;
#pragma unroll
  for(int nd=0;nd<4;nd++) OUT[(n0+nd)*128 + k] = u[nd];
}

// ---------------- K3: edge logits + softmax + agg + @Wo (R7 structure + MLP-split) ----
__global__ __launch_bounds__(256) void k_attn(
    const float* __restrict__ trans, const float* __restrict__ Wa1,
    const float* __restrict__ ba1, const float* __restrict__ Wa2,
    const float* __restrict__ Wo,
    const float* __restrict__ U, const float* __restrict__ V,
    const float* __restrict__ P, const float* __restrict__ Trel,
    const int* __restrict__ srcs, float* __restrict__ Y)
{
  __shared__ int   s_src[NSLOT];
  __shared__ int   s_val[NSLOT];
  __shared__ float s_dist[NSLOT];
  __shared__ __align__(16) float s_H[NSLOT*HPAD];   // 22176 B
  __shared__ __align__(16) float s_mux[NSLOT*32];   // 5376 B: rbf(42*16) | wa2t(8*132) | agg(4*260)
  __shared__ float s_att[NSLOT*8];

  int b = blockIdx.x, t = threadIdx.x;
  int d = xcd_swz(b);
  int pos = d & (CHAIN-1);
  int k = t & 127, grp = t >> 7;

  // stage 0: edge meta
  if(t < NSLOT){
    int src;
    if(t < NFIX)      src = srcs[d*NFIX + t];
    else if(t == NFIX) src = (pos > 0)       ? d-1 : d;
    else               src = (pos < CHAIN-1) ? d+1 : d;
    s_src[t] = src;
    float dx = trans[src*3+0]-trans[d*3+0];
    float dy = trans[src*3+1]-trans[d*3+1];
    float dz = trans[src*3+2]-trans[d*3+2];
    float dist = sqrtf(dx*dx + dy*dy + dz*dz + 1e-12f);
    s_dist[t] = dist;
    s_val[t] = (dist > 1e-3f) ? 1 : 0;
  }

  // per-thread rbf weight column (16 floats -> stays in VGPRs)
  float wreg[16];
#pragma unroll
  for(int f=0; f<16; f++) wreg[f] = Wa1[(262+f)*128 + k];
  float ubias = ba1[k] + V[d*128 + k];
  __syncthreads();

  // stage 1: rbf[42][16]
  for(int i=t; i<NSLOT*16; i+=256){
    int e = i >> 4, f = i & 15;
    float zz = (s_dist[e] - (float)f * (20.0f/15.0f)) * 0.8f;
    s_mux[i] = expf(-(zz*zz));
  }
  __syncthreads();

  // stage 2a: gather U[src]+Trel[rel] for my 21 edges -> s_H (all 42 loads in flight)
  for(int e = grp; e < NSLOT; e += 2){
    int src = s_src[e];
    s_H[e*HPAD + k] = U[src*128 + k] + Trel[(src - d + 511)*128 + k];
  }
  // stage 2b: H = leaky(ubias + gathered + rbf.wreg)  (same thread owns same (e,k))
  for(int e = grp; e < NSLOT; e += 2){
    float h = ubias + s_H[e*HPAD + k];
    const float4* rp = (const float4*)(s_mux + e*16);
#pragma unroll
    for(int q=0; q<4; q++){
      float4 ev = rp[q];
      h += ev.x*wreg[4*q+0] + ev.y*wreg[4*q+1] + ev.z*wreg[4*q+2] + ev.w*wreg[4*q+3];
    }
    h = (h >= 0.0f) ? h : 0.01f*h;
    s_H[e*HPAD + k] = h;
  }
  __syncthreads();

  // stage 2.5: Wa2^T -> s_mux (rbf dead)
  for(int i=t; i<1024; i+=256){
    int kk = i >> 3, h = i & 7;
    s_mux[h*HPAD + kk] = Wa2[i];
  }
  __syncthreads();

  // stage 3: logits[e][h] = H[e] . Wa2[:,h]  (336 parallel float4 dots)
  for(int p = t; p < NSLOT*8; p += 256){
    int e = p >> 3, h = p & 7;
    const float4* Hp = (const float4*)(s_H + e*HPAD);
    const float4* Wp = (const float4*)(s_mux + h*HPAD);
    float acc = 0.f;
#pragma unroll
    for(int q=0; q<32; q++){
      float4 a = Hp[q], w = Wp[q];
      acc += a.x*w.x + a.y*w.y + a.z*w.z + a.w*w.w;
    }
    s_att[p] = s_val[e] ? acc : -1e30f;
  }
  __syncthreads();

  // stage 4: per-head softmax
  if(t < 64){
    int h = t & 7, g = t >> 3;
    float m = -INFINITY;
    for(int e=g; e<NSLOT; e+=8) m = fmaxf(m, s_att[e*8+h]);
    for(int off=8; off<64; off<<=1) m = fmaxf(m, __shfl_xor(m, off, 64));
    m = (m > -5e29f) ? m : 0.0f;
    float z = 0.0f;
    for(int e=g; e<NSLOT; e+=8){
      float p = expf(s_att[e*8+h] - m);
      s_att[e*8+h] = p; z += p;
    }
    for(int off=8; off<64; off<<=1) z += __shfl_xor(z, off, 64);
    float inv = 1.0f / (z + 1e-9f);
    for(int e=g; e<NSLOT; e+=8) s_att[e*8+h] *= inv;
  }
  __syncthreads();

  // stage 5: agg[u=t][c] = sum_e attn[e][u>>5] * P[src][u][c]
  {
    int h = t >> 5;
    float a0=0.f,a1=0.f,a2=0.f,a3=0.f;
    for(int e=0;e<NSLOT;e++){
      float w = s_att[e*8 + h];
      float4 p4 = *(const float4*)(P + (size_t)s_src[e]*1024 + t*4);
      a0 += w*p4.x; a1 += w*p4.y; a2 += w*p4.z; a3 += w*p4.w;
    }
    s_mux[0*AGPAD + t] = a0;
    s_mux[1*AGPAD + t] = a1;
    s_mux[2*AGPAD + t] = a2;
    s_mux[3*AGPAD + t] = a3;
  }
  __syncthreads();

  // stage 6: Y[d][c][k] = agg[c] @ Wo (coalesced weight loads, shared across c-pair)
  {
    int cp = grp*2;
    const float* g0 = s_mux + cp*AGPAD;
    const float* g1 = s_mux + (cp+1)*AGPAD;
    float x0=0.f, x1=0.f;
    for(int u=0; u<256; u+=4){
      float w0=Wo[(u+0)*128+k], w1=Wo[(u+1)*128+k], w2=Wo[(u+2)*128+k], w3=Wo[(u+3)*128+k];
      float4 a0 = *(const float4*)(g0 + u);
      float4 a1 = *(const float4*)(g1 + u);
      x0 += a0.x*w0 + a0.y*w1 + a0.z*w2 + a0.w*w3;
      x1 += a1.x*w0 + a1.y*w1 + a1.z*w2 + a1.w*w3;
    }
    Y[d*512 + cp*128 + k]     = x0;
    Y[d*512 + (cp+1)*128 + k] = x1;
  }
}

// ---------------- K5: per-node MLP chain, 4 nodes/block ------------
__global__ __launch_bounds__(256) void k_node(
    const float* __restrict__ rots, const float* __restrict__ trans,
    const float* __restrict__ Y,
    const float* __restrict__ Wg, const float* __restrict__ Wf1,
    const float* __restrict__ Wf2, const float* __restrict__ Wr1,
    const float* __restrict__ br1, const float* __restrict__ Wr2,
    const float* __restrict__ br2, const float* __restrict__ Wr3,
    const float* __restrict__ br3, const float* __restrict__ Wt,
    const int* __restrict__ nmask, float* __restrict__ out)
{
  __shared__ __align__(16) float s_y[4][4][128];
  __shared__ __align__(16) float s_t1[4][128];
  __shared__ __align__(16) float s_bb0[4][128];
  __shared__ __align__(16) float s_gv[4][3][128];
  __shared__ __align__(16) float s_h1[4][256];
  __shared__ __align__(16) float s_h2[4][128];
  __shared__ float s_sc[4][8];

  int b = blockIdx.x, t = threadIdx.x;
  int half = t >> 7, k = t & 127;
  int nb = half*2;
  int dbase = b*4;
  for(int i=t; i<4*512; i+=256){
    int nd = i>>9, c=(i>>7)&3, kk=i&127;
    s_y[nd][c][kk] = Y[(dbase+nd)*512 + c*128 + kk];
  }
  __syncthreads();

  float g[2]={0.f,0.f}, f1[2]={0.f,0.f};
  for(int j=0;j<128;j+=4){
    float wg0=Wg[(j+0)*128+k], wg1=Wg[(j+1)*128+k], wg2=Wg[(j+2)*128+k], wg3=Wg[(j+3)*128+k];
    float wf0=Wf1[(j+0)*128+k], wf1_=Wf1[(j+1)*128+k], wf2_=Wf1[(j+2)*128+k], wf3=Wf1[(j+3)*128+k];
#pragma unroll
    for(int nn=0;nn<2;nn++){
      float4 yv = *(const float4*)&s_y[nb+nn][0][j];
      g[nn]  += yv.x*wg0 + yv.y*wg1 + yv.z*wg2 + yv.w*wg3;
      f1[nn] += yv.x*wf0 + yv.y*wf1_ + yv.z*wf2_ + yv.w*wf3;
    }
  }
  float gate[2];
#pragma unroll
  for(int nn=0;nn<2;nn++){
    gate[nn] = 1.0f/(1.0f + expf(-g[nn]));
    s_t1[nb+nn][k] = fmaxf(f1[nn], 0.0f);
  }
  __syncthreads();

  float f0[2]={0.f,0.f};
  for(int j=0;j<128;j+=4){
    float w0=Wf2[(j+0)*128+k], w1=Wf2[(j+1)*128+k], w2=Wf2[(j+2)*128+k], w3=Wf2[(j+3)*128+k];
#pragma unroll
    for(int nn=0;nn<2;nn++){
      float4 tv = *(const float4*)&s_t1[nb+nn][j];
      f0[nn] += tv.x*w0 + tv.y*w1 + tv.z*w2 + tv.w*w3;
    }
  }
#pragma unroll
  for(int nn=0;nn<2;nn++){
    int d = dbase + nb + nn;
    float bb0 = s_y[nb+nn][0][k] + f0[nn];
    s_bb0[nb+nn][k] = bb0;
    out[OUT_BB + d*512 + k] = bb0;
#pragma unroll
    for(int c=1;c<4;c++){
      float v = s_y[nb+nn][c][k] * gate[nn];
      s_gv[nb+nn][c-1][k] = v;
      out[OUT_BB + d*512 + c*128 + k] = v;
    }
  }
  __syncthreads();

  float a1[2], a2[2];
  a1[0]=a1[1]=br1[k]; a2[0]=a2[1]=br1[128+k];
  for(int j=0;j<128;j+=4){
    float w10=Wr1[(j+0)*256+k],     w11=Wr1[(j+1)*256+k],     w12=Wr1[(j+2)*256+k],     w13=Wr1[(j+3)*256+k];
    float w20=Wr1[(j+0)*256+128+k], w21=Wr1[(j+1)*256+128+k], w22=Wr1[(j+2)*256+128+k], w23=Wr1[(j+3)*256+128+k];
#pragma unroll
    for(int nn=0;nn<2;nn++){
      float4 bv = *(const float4*)&s_bb0[nb+nn][j];
      a1[nn] += bv.x*w10 + bv.y*w11 + bv.z*w12 + bv.w*w13;
      a2[nn] += bv.x*w20 + bv.y*w21 + bv.z*w22 + bv.w*w23;
    }
  }
#pragma unroll
  for(int nn=0;nn<2;nn++){
    s_h1[nb+nn][k] = fmaxf(a1[nn], 0.0f);
    s_h1[nb+nn][128+k] = fmaxf(a2[nn], 0.0f);
  }
  __syncthreads();

  float a[2]; a[0]=a[1]=br2[k];
  for(int j=0;j<256;j+=4){
    float w0=Wr2[(j+0)*128+k], w1=Wr2[(j+1)*128+k], w2=Wr2[(j+2)*128+k], w3=Wr2[(j+3)*128+k];
#pragma unroll
    for(int nn=0;nn<2;nn++){
      float4 hv = *(const float4*)&s_h1[nb+nn][j];
      a[nn] += hv.x*w0 + hv.y*w1 + hv.z*w2 + hv.w*w3;
    }
  }
#pragma unroll
  for(int nn=0;nn<2;nn++) s_h2[nb+nn][k] = fmaxf(a[nn], 0.0f);
  __syncthreads();

  if(t < 12){
    int nd = t/3, r = t%3;
    float q = br3[r];
    for(int kk=0;kk<128;kk++) q += s_h2[nd][kk] * Wr3[kk*6 + r];
    s_sc[nd][r] = q;
  } else if(t >= 32 && t < 44){
    int q2 = t-32; int nd = q2/3, i = q2%3;
    float s = 0.f;
    for(int kk=0;kk<128;kk++) s += s_gv[nd][i][kk] * Wt[kk];
    s_sc[nd][4+i] = s;
  }
  __syncthreads();

  if(t < 4){
    int d = dbase + t;
    int nz = nmask[d];
    float q1=s_sc[t][0], q2=s_sc[t][1], q3=s_sc[t][2];
    float nrm = sqrtf(1.0f + q1*q1 + q2*q2 + q3*q3);
    float w=1.0f/nrm, x=q1/nrm, y=q2/nrm, z=q3/nrm;
    float Ru[3][3];
    Ru[0][0]=1.f-2.f*(y*y+z*z); Ru[0][1]=2.f*(x*y-w*z);     Ru[0][2]=2.f*(x*z+w*y);
    Ru[1][0]=2.f*(x*y+w*z);     Ru[1][1]=1.f-2.f*(x*x+z*z); Ru[1][2]=2.f*(y*z-w*x);
    Ru[2][0]=2.f*(x*z-w*y);     Ru[2][1]=2.f*(y*z+w*x);     Ru[2][2]=1.f-2.f*(x*x+y*y);
    for(int i=0;i<3;i++){
      for(int j=0;j<3;j++){
        float rv;
        if(nz){
          rv = rots[d*9+i*3+0]*Ru[0][j] + rots[d*9+i*3+1]*Ru[1][j] + rots[d*9+i*3+2]*Ru[2][j];
        } else {
          rv = rots[d*9+i*3+j];
        }
        out[OUT_ROT + d*9 + i*3 + j] = rv;
      }
      float tv = trans[d*3+i];
      out[OUT_TRANS + d*3 + i] = nz ? (tv + s_sc[t][4+i]) : tv;
    }
  }
}

extern "C" void kernel_launch(void* const* d_in, const int* in_sizes, int n_in,
                              void* d_out, int out_size, void* d_ws, size_t ws_size,
                              hipStream_t stream)
{
  (void)in_sizes; (void)n_in; (void)out_size; (void)ws_size;
  const float* rots = (const float*)d_in[0];
  const float* trans = (const float*)d_in[1];
  const float* nf   = (const float*)d_in[2];
  const float* Wa1  = (const float*)d_in[3];
  const float* ba1  = (const float*)d_in[4];
  const float* Wa2  = (const float*)d_in[5];
  const float* Wv   = (const float*)d_in[6];
  const float* Wo   = (const float*)d_in[7];
  const float* Wg   = (const float*)d_in[8];
  const float* Wf1  = (const float*)d_in[9];
  const float* Wf2  = (const float*)d_in[10];
  const float* Wr1  = (const float*)d_in[11];
  const float* br1  = (const float*)d_in[12];
  const float* Wr2  = (const float*)d_in[13];
  const float* br2  = (const float*)d_in[14];
  const float* Wr3  = (const float*)d_in[15];
  const float* br3  = (const float*)d_in[16];
  const float* Wt   = (const float*)d_in[17];
  const int* xmask  = (const int*)d_in[19];
  const int* nmask  = (const int*)d_in[20];

  float* P = (float*)d_ws;                 // NN*1024 f32  (8 MB), layout [n][u][c]
  float* U = P + NN*1024;                  // NN*128       (1 MB)
  float* V = U + NN*128;                   // NN*128       (1 MB)
  int* srcs = (int*)(V + NN*128);          // NN*40 int    (320 KB)
  float* Y  = (float*)(srcs + NN*NFIX);    // NN*512 f32   (4 MB)
  float* Trel = Y + NN*512;                // 1023*128 f32 (0.52 MB)

  k_pretop<<<NN + 512 + 512, 256, 0, stream>>>(rots, trans, nf, Wa1, Wv,
                                               xmask, nmask, P, U, V, srcs, Trel);
  k_attn<<<NN, 256, 0, stream>>>(trans, Wa1, ba1, Wa2, Wo, U, V, P, Trel, srcs, Y);
  k_node<<<NN/4, 256, 0, stream>>>(rots, trans, Y, Wg, Wf1, Wf2,
                                   Wr1, br1, Wr2, br2, Wr3, br3, Wt,
                                   nmask, (float*)d_out);
}

// Round 11
// 139.799 us; speedup vs baseline: 1.2670x; 1.0181x over previous
//
#include <hip/hip_runtime.h>
#include <hip/hip_bf16.h>
#include <math.h>

#define NN 2048
#define CHAIN 512
#define KNN 30
#define LRK 10
#define NFIX 40
#define NSLOT 42
#define HPAD 132
#define AGPAD 260
#define NREL 1023

#define OUT_ROT 0
#define OUT_TRANS (NN*9)
#define OUT_BB (NN*9 + NN*3)

#define THREEFRY_PARTITIONABLE 1

__device__ __forceinline__ int xcd_swz(int b){ return ((b & 7) << 8) | (b >> 3); }

// ---------------- threefry2x32, key = (0, 42) ----------------
__device__ __forceinline__ unsigned rotl32(unsigned x, unsigned r){ return (x<<r)|(x>>(32u-r)); }

__device__ __forceinline__ void tf_block(unsigned &x0, unsigned &x1){
  const unsigned k0 = 0u, k1 = 42u, k2 = 0x1BD11BDAu ^ 0u ^ 42u;
  x0 += k0; x1 += k1;
#define TFR(a) x0 += x1; x1 = rotl32(x1,(a)); x1 ^= x0;
  TFR(13) TFR(15) TFR(26) TFR(6)   x0 += k1; x1 += k2 + 1u;
  TFR(17) TFR(29) TFR(16) TFR(24)  x0 += k2; x1 += k0 + 2u;
  TFR(13) TFR(15) TFR(26) TFR(6)   x0 += k0; x1 += k1 + 3u;
  TFR(17) TFR(29) TFR(16) TFR(24)  x0 += k1; x1 += k2 + 4u;
  TFR(13) TFR(15) TFR(26) TFR(6)   x0 += k2; x1 += k0 + 5u;
#undef TFR
}

__device__ __forceinline__ float gumbel_from_bits(unsigned bits){
  float f = __uint_as_float((bits >> 9) | 0x3f800000u) - 1.0f;
  const float tiny = 1.17549435e-38f;
  float u = fmaxf(tiny, f * (1.0f - tiny) + tiny);
  return -logf(-logf(u));
}

__device__ __forceinline__ float gumbel_at(unsigned p){
#if THREEFRY_PARTITIONABLE
  unsigned x0 = 0u, x1 = p;
  tf_block(x0, x1);
  return gumbel_from_bits(x0 ^ x1);
#else
  const unsigned HALF = (NN*(unsigned)NN)/2u;
  unsigned c0, c1; bool lo = p < HALF;
  if(lo){ c0 = p; c1 = p + HALF; } else { c0 = p - HALF; c1 = p; }
  tf_block(c0, c1);
  return gumbel_from_bits(lo ? c0 : c1);
#endif
}

// ---------------- K1: fused topk / prep / Trel (block-role split) ------------
__global__ __launch_bounds__(256) void k_pretop(
    const float* __restrict__ rots, const float* __restrict__ trans,
    const float* __restrict__ nf, const float* __restrict__ Wa1,
    const float* __restrict__ Wv,
    const int* __restrict__ xmask, const int* __restrict__ nmask,
    float* __restrict__ P, float* __restrict__ U, float* __restrict__ V,
    int* __restrict__ srcs, float* __restrict__ Trel)
{
  __shared__ __align__(16) char smem[4*4*132*4];
  int bb = blockIdx.x, t = threadIdx.x;

  if(bb >= NN + 512){
    // ---------------- Trel role ----------------
    int r = (bb - (NN+512))*2 + (t >> 7);
    int k = t & 127;
    if(r < NREL){
      float rel = (float)(r - 511);
      float acc = 0.f;
#pragma unroll
      for(int j=0;j<8;j++){
        float fr = expf((float)(2*j) * (float)(-0.5756462732485115));
        float ang = rel * fr;
        acc += cosf(ang) * Wa1[(278+j)*128 + k];
        acc += sinf(ang) * Wa1[(286+j)*128 + k];
      }
      Trel[r*128 + k] = acc;
    }
    return;
  }

  if(bb < NN){
    // ---------------- topk role ----------------
    unsigned* s_kk = (unsigned*)smem;          // [512]
    unsigned* s_lk = s_kk + CHAIN;             // [512]
    int i = bb;
    int base = (i >> 9) << 9;
    float tx = trans[i*3+0], ty = trans[i*3+1], tz = trans[i*3+2];
    for(int q=t; q<CHAIN; q+=256){
      int j = base + q;
      float dx = __fsub_rn(trans[j*3+0], tx);
      float dy = __fsub_rn(trans[j*3+1], ty);
      float dz = __fsub_rn(trans[j*3+2], tz);
      float d2 = __fadd_rn(__fadd_rn(__fmul_rn(dx,dx),__fmul_rn(dy,dy)),__fmul_rn(dz,dz));
      bool val = (j != i);
      float dm = val ? d2 : 1e30f;
      s_kk[q] = __float_as_uint(dm) ^ 0x80000000u;
      if(val){
        float g = gumbel_at((unsigned)(i*NN + j));
        float sc = __fadd_rn(__fmul_rn(-1.5f, logf(dm)), g);
        unsigned b = __float_as_uint(sc);
        unsigned ord = b ^ ((b & 0x80000000u) ? 0xFFFFFFFFu : 0x80000000u);
        s_lk[q] = ~ord;
      } else {
        s_lk[q] = 0xFFFFFFFFu;
      }
    }
    __syncthreads();
    if(t < 128){
      int w = t >> 6, lane = t & 63;
      unsigned* arr = w ? s_lk : s_kk;
      int K = w ? LRK : KNN;
      int outoff = w ? KNN : 0;
      // load my 8 keys into registers; tombstone selection (no LDS after this)
      unsigned long long k0_ = ((unsigned long long)arr[lane      ]<<32) | (unsigned)(lane);
      unsigned long long k1_ = ((unsigned long long)arr[lane + 64 ]<<32) | (unsigned)(lane+64);
      unsigned long long k2_ = ((unsigned long long)arr[lane + 128]<<32) | (unsigned)(lane+128);
      unsigned long long k3_ = ((unsigned long long)arr[lane + 192]<<32) | (unsigned)(lane+192);
      unsigned long long k4_ = ((unsigned long long)arr[lane + 256]<<32) | (unsigned)(lane+256);
      unsigned long long k5_ = ((unsigned long long)arr[lane + 320]<<32) | (unsigned)(lane+320);
      unsigned long long k6_ = ((unsigned long long)arr[lane + 384]<<32) | (unsigned)(lane+384);
      unsigned long long k7_ = ((unsigned long long)arr[lane + 448]<<32) | (unsigned)(lane+448);
      unsigned long long lmin;
      {
        unsigned long long a01 = k0_<k1_?k0_:k1_, a23 = k2_<k3_?k2_:k3_;
        unsigned long long a45 = k4_<k5_?k4_:k5_, a67 = k6_<k7_?k6_:k7_;
        unsigned long long a03 = a01<a23?a01:a23, a47 = a45<a67?a45:a67;
        lmin = a03<a47?a03:a47;
      }
      for(int k=0;k<K;k++){
        unsigned long long r = lmin;
        for(int off=32; off; off>>=1){
          unsigned long long o = __shfl_xor(r, off, 64);
          if(o < r) r = o;
        }
        if(lane == 0) srcs[i*NFIX + outoff + k] = base + (int)(unsigned)(r & 0xffffffffull);
        if(r == lmin){   // winner lane (keys unique): tombstone + recompute local min
          if(k0_ == r) k0_ = ~0ull;
          if(k1_ == r) k1_ = ~0ull;
          if(k2_ == r) k2_ = ~0ull;
          if(k3_ == r) k3_ = ~0ull;
          if(k4_ == r) k4_ = ~0ull;
          if(k5_ == r) k5_ = ~0ull;
          if(k6_ == r) k6_ = ~0ull;
          if(k7_ == r) k7_ = ~0ull;
          unsigned long long a01 = k0_<k1_?k0_:k1_, a23 = k2_<k3_?k2_:k3_;
          unsigned long long a45 = k4_<k5_?k4_:k5_, a67 = k6_<k7_?k6_:k7_;
          unsigned long long a03 = a01<a23?a01:a23, a47 = a45<a67?a45:a67;
          lmin = a03<a47?a03:a47;
        }
      }
    }
    return;
  }

  // ---------------- prep role (4 nodes) ----------------
  float (*fr)[4][132] = (float (*)[4][132])smem;
  int n0 = (bb - NN)*4;
  for(int i=t; i<2048; i+=256){
    int nd = i>>9, c = (i>>7)&3, kk = i&127;
    fr[nd][c][kk] = nf[(n0+nd)*512 + c*128 + kk];
  }
  if(t < 4){
    fr[t][0][128] = 0.0f; fr[t][0][129] = 0.0f;
    fr[t][0][130] = (nmask[n0+t] != 0 && xmask[n0+t] == 0) ? 1.0f : 0.0f;
  } else if(t >= 16 && t < 52){
    int q = t - 16; int nd = q/9, r = q%9, a = r/3, i = r%3;
    int n = n0 + nd;
    const float BB[3][3] = {{-0.525f,1.363f,0.0f},{0.f,0.f,0.f},{1.526f,0.f,0.f}};
    float bb_ = rots[n*9+i*3+0]*BB[a][0] + rots[n*9+i*3+1]*BB[a][1]
              + rots[n*9+i*3+2]*BB[a][2] + trans[n*3+i];
    fr[nd][1+i][128+a] = bb_;
  }
  __syncthreads();

  float a[4][4];
#pragma unroll
  for(int nd=0;nd<4;nd++)
#pragma unroll
    for(int c=0;c<4;c++) a[nd][c]=0.f;
  for(int j=0;j<128;j+=4){
    float w0=Wv[(j+0)*256+t], w1=Wv[(j+1)*256+t], w2=Wv[(j+2)*256+t], w3=Wv[(j+3)*256+t];
#pragma unroll
    for(int nd=0;nd<4;nd++){
#pragma unroll
      for(int c=0;c<4;c++){
        float4 f4 = *(const float4*)&fr[nd][c][j];
        a[nd][c] += f4.x*w0 + f4.y*w1 + f4.z*w2 + f4.w*w3;
      }
    }
  }
  for(int j=128;j<131;j++){
    float w = Wv[j*256+t];
#pragma unroll
    for(int nd=0;nd<4;nd++)
#pragma unroll
      for(int c=0;c<4;c++) a[nd][c] += fr[nd][c][j]*w;
  }
#pragma unroll
  for(int nd=0;nd<4;nd++){
    float4 v4; v4.x=a[nd][0]; v4.y=a[nd][1]; v4.z=a[nd][2]; v4.w=a[nd][3];
    *(float4*)&P[(n0+nd)*1024 + t*4] = v4;   // layout [n][u][c]
  }

  int k = t & 127;
  int isV = t >> 7;
  const float* Wcol = Wa1 + (isV ? 131*128 : 0);
  float u[4] = {0.f,0.f,0.f,0.f};
  for(int j=0;j<128;j+=4){
    float w0=Wcol[(j+0)*128+k], w1=Wcol[(j+1)*128+k], w2=Wcol[(j+2)*128+k], w3=Wcol[(j+3)*128+k];
#pragma unroll
    for(int nd=0;nd<4;nd++){
      float4 f4 = *(const float4*)&fr[nd][0][j];
      u[nd] += f4.x*w0 + f4.y*w1 + f4.z*w2 + f4.w*w3;
    }
  }
  for(int j=128;j<131;j++){
    float w = Wcol[j*128+k];
#pragma unroll
    for(int nd=0;nd<4;nd++) u[nd] += fr[nd][0][j]*w;
  }
  float* OUT = isV ? V : U;
#pragma unroll
  for(int nd=0;nd<4;nd++) OUT[(n0+nd)*128 + k] = u[nd];
}

// ---------------- K3: edge logits + softmax + agg + @Wo (unchanged from R10) ----
__global__ __launch_bounds__(256) void k_attn(
    const float* __restrict__ trans, const float* __restrict__ Wa1,
    const float* __restrict__ ba1, const float* __restrict__ Wa2,
    const float* __restrict__ Wo,
    const float* __restrict__ U, const float* __restrict__ V,
    const float* __restrict__ P, const float* __restrict__ Trel,
    const int* __restrict__ srcs, float* __restrict__ Y)
{
  __shared__ int   s_src[NSLOT];
  __shared__ int   s_val[NSLOT];
  __shared__ float s_dist[NSLOT];
  __shared__ __align__(16) float s_H[NSLOT*HPAD];   // 22176 B
  __shared__ __align__(16) float s_mux[NSLOT*32];   // 5376 B: rbf | wa2t | agg
  __shared__ float s_att[NSLOT*8];

  int b = blockIdx.x, t = threadIdx.x;
  int d = xcd_swz(b);
  int pos = d & (CHAIN-1);
  int k = t & 127, grp = t >> 7;

  if(t < NSLOT){
    int src;
    if(t < NFIX)      src = srcs[d*NFIX + t];
    else if(t == NFIX) src = (pos > 0)       ? d-1 : d;
    else               src = (pos < CHAIN-1) ? d+1 : d;
    s_src[t] = src;
    float dx = trans[src*3+0]-trans[d*3+0];
    float dy = trans[src*3+1]-trans[d*3+1];
    float dz = trans[src*3+2]-trans[d*3+2];
    float dist = sqrtf(dx*dx + dy*dy + dz*dz + 1e-12f);
    s_dist[t] = dist;
    s_val[t] = (dist > 1e-3f) ? 1 : 0;
  }

  float wreg[16];
#pragma unroll
  for(int f=0; f<16; f++) wreg[f] = Wa1[(262+f)*128 + k];
  float ubias = ba1[k] + V[d*128 + k];
  __syncthreads();

  for(int i=t; i<NSLOT*16; i+=256){
    int e = i >> 4, f = i & 15;
    float zz = (s_dist[e] - (float)f * (20.0f/15.0f)) * 0.8f;
    s_mux[i] = expf(-(zz*zz));
  }
  __syncthreads();

  for(int e = grp; e < NSLOT; e += 2){
    int src = s_src[e];
    s_H[e*HPAD + k] = U[src*128 + k] + Trel[(src - d + 511)*128 + k];
  }
  for(int e = grp; e < NSLOT; e += 2){
    float h = ubias + s_H[e*HPAD + k];
    const float4* rp = (const float4*)(s_mux + e*16);
#pragma unroll
    for(int q=0; q<4; q++){
      float4 ev = rp[q];
      h += ev.x*wreg[4*q+0] + ev.y*wreg[4*q+1] + ev.z*wreg[4*q+2] + ev.w*wreg[4*q+3];
    }
    h = (h >= 0.0f) ? h : 0.01f*h;
    s_H[e*HPAD + k] = h;
  }
  __syncthreads();

  for(int i=t; i<1024; i+=256){
    int kk = i >> 3, h = i & 7;
    s_mux[h*HPAD + kk] = Wa2[i];
  }
  __syncthreads();

  for(int p = t; p < NSLOT*8; p += 256){
    int e = p >> 3, h = p & 7;
    const float4* Hp = (const float4*)(s_H + e*HPAD);
    const float4* Wp = (const float4*)(s_mux + h*HPAD);
    float acc = 0.f;
#pragma unroll
    for(int q=0; q<32; q++){
      float4 a = Hp[q], w = Wp[q];
      acc += a.x*w.x + a.y*w.y + a.z*w.z + a.w*w.w;
    }
    s_att[p] = s_val[e] ? acc : -1e30f;
  }
  __syncthreads();

  if(t < 64){
    int h = t & 7, g = t >> 3;
    float m = -INFINITY;
    for(int e=g; e<NSLOT; e+=8) m = fmaxf(m, s_att[e*8+h]);
    for(int off=8; off<64; off<<=1) m = fmaxf(m, __shfl_xor(m, off, 64));
    m = (m > -5e29f) ? m : 0.0f;
    float z = 0.0f;
    for(int e=g; e<NSLOT; e+=8){
      float p = expf(s_att[e*8+h] - m);
      s_att[e*8+h] = p; z += p;
    }
    for(int off=8; off<64; off<<=1) z += __shfl_xor(z, off, 64);
    float inv = 1.0f / (z + 1e-9f);
    for(int e=g; e<NSLOT; e+=8) s_att[e*8+h] *= inv;
  }
  __syncthreads();

  {
    int h = t >> 5;
    float a0=0.f,a1=0.f,a2=0.f,a3=0.f;
    for(int e=0;e<NSLOT;e++){
      float w = s_att[e*8 + h];
      float4 p4 = *(const float4*)(P + (size_t)s_src[e]*1024 + t*4);
      a0 += w*p4.x; a1 += w*p4.y; a2 += w*p4.z; a3 += w*p4.w;
    }
    s_mux[0*AGPAD + t] = a0;
    s_mux[1*AGPAD + t] = a1;
    s_mux[2*AGPAD + t] = a2;
    s_mux[3*AGPAD + t] = a3;
  }
  __syncthreads();

  {
    int cp = grp*2;
    const float* g0 = s_mux + cp*AGPAD;
    const float* g1 = s_mux + (cp+1)*AGPAD;
    float x0=0.f, x1=0.f;
    for(int u=0; u<256; u+=4){
      float w0=Wo[(u+0)*128+k], w1=Wo[(u+1)*128+k], w2=Wo[(u+2)*128+k], w3=Wo[(u+3)*128+k];
      float4 a0 = *(const float4*)(g0 + u);
      float4 a1 = *(const float4*)(g1 + u);
      x0 += a0.x*w0 + a0.y*w1 + a0.z*w2 + a0.w*w3;
      x1 += a1.x*w0 + a1.y*w1 + a1.z*w2 + a1.w*w3;
    }
    Y[d*512 + cp*128 + k]     = x0;
    Y[d*512 + (cp+1)*128 + k] = x1;
  }
}

// ---------------- K5: per-node MLP chain, 4 nodes/block, 512 threads (1 node / 128t) ----
__global__ __launch_bounds__(512) void k_node(
    const float* __restrict__ rots, const float* __restrict__ trans,
    const float* __restrict__ Y,
    const float* __restrict__ Wg, const float* __restrict__ Wf1,
    const float* __restrict__ Wf2, const float* __restrict__ Wr1,
    const float* __restrict__ br1, const float* __restrict__ Wr2,
    const float* __restrict__ br2, const float* __restrict__ Wr3,
    const float* __restrict__ br3, const float* __restrict__ Wt,
    const int* __restrict__ nmask, float* __restrict__ out)
{
  __shared__ __align__(16) float s_y[4][4][128];
  __shared__ __align__(16) float s_t1[4][128];
  __shared__ __align__(16) float s_bb0[4][128];
  __shared__ __align__(16) float s_gv[4][3][128];
  __shared__ __align__(16) float s_h1[4][256];
  __shared__ __align__(16) float s_h2[4][128];
  __shared__ float s_sc[4][8];

  int b = blockIdx.x, t = threadIdx.x;
  int nd = t >> 7, k = t & 127;   // node 0..3, dim 0..127
  int dbase = b*4;
  int d = dbase + nd;
  for(int i=t; i<4*512; i+=512){
    int n2 = i>>9, c=(i>>7)&3, kk=i&127;
    s_y[n2][c][kk] = Y[(dbase+n2)*512 + c*128 + kk];
  }
  __syncthreads();

  float g=0.f, f1=0.f;
  for(int j=0;j<128;j+=4){
    float wg0=Wg[(j+0)*128+k], wg1=Wg[(j+1)*128+k], wg2=Wg[(j+2)*128+k], wg3=Wg[(j+3)*128+k];
    float wf0=Wf1[(j+0)*128+k], wf1_=Wf1[(j+1)*128+k], wf2_=Wf1[(j+2)*128+k], wf3=Wf1[(j+3)*128+k];
    float4 yv = *(const float4*)&s_y[nd][0][j];
    g  += yv.x*wg0 + yv.y*wg1 + yv.z*wg2 + yv.w*wg3;
    f1 += yv.x*wf0 + yv.y*wf1_ + yv.z*wf2_ + yv.w*wf3;
  }
  float gate = 1.0f/(1.0f + expf(-g));
  s_t1[nd][k] = fmaxf(f1, 0.0f);
  __syncthreads();

  float f0=0.f;
  for(int j=0;j<128;j+=4){
    float w0=Wf2[(j+0)*128+k], w1=Wf2[(j+1)*128+k], w2=Wf2[(j+2)*128+k], w3=Wf2[(j+3)*128+k];
    float4 tv = *(const float4*)&s_t1[nd][j];
    f0 += tv.x*w0 + tv.y*w1 + tv.z*w2 + tv.w*w3;
  }
  {
    float bb0 = s_y[nd][0][k] + f0;
    s_bb0[nd][k] = bb0;
    out[OUT_BB + d*512 + k] = bb0;
#pragma unroll
    for(int c=1;c<4;c++){
      float v = s_y[nd][c][k] * gate;
      s_gv[nd][c-1][k] = v;
      out[OUT_BB + d*512 + c*128 + k] = v;
    }
  }
  __syncthreads();

  float a1 = br1[k], a2 = br1[128+k];
  for(int j=0;j<128;j+=4){
    float w10=Wr1[(j+0)*256+k],     w11=Wr1[(j+1)*256+k],     w12=Wr1[(j+2)*256+k],     w13=Wr1[(j+3)*256+k];
    float w20=Wr1[(j+0)*256+128+k], w21=Wr1[(j+1)*256+128+k], w22=Wr1[(j+2)*256+128+k], w23=Wr1[(j+3)*256+128+k];
    float4 bv = *(const float4*)&s_bb0[nd][j];
    a1 += bv.x*w10 + bv.y*w11 + bv.z*w12 + bv.w*w13;
    a2 += bv.x*w20 + bv.y*w21 + bv.z*w22 + bv.w*w23;
  }
  s_h1[nd][k] = fmaxf(a1, 0.0f);
  s_h1[nd][128+k] = fmaxf(a2, 0.0f);
  __syncthreads();

  float a = br2[k];
  for(int j=0;j<256;j+=4){
    float w0=Wr2[(j+0)*128+k], w1=Wr2[(j+1)*128+k], w2=Wr2[(j+2)*128+k], w3=Wr2[(j+3)*128+k];
    float4 hv = *(const float4*)&s_h1[nd][j];
    a += hv.x*w0 + hv.y*w1 + hv.z*w2 + hv.w*w3;
  }
  s_h2[nd][k] = fmaxf(a, 0.0f);
  __syncthreads();

  if(t < 12){
    int n2 = t/3, r = t%3;
    float q = br3[r];
    for(int kk=0;kk<128;kk++) q += s_h2[n2][kk] * Wr3[kk*6 + r];
    s_sc[n2][r] = q;
  } else if(t >= 32 && t < 44){
    int q2 = t-32; int n2 = q2/3, i = q2%3;
    float s = 0.f;
    for(int kk=0;kk<128;kk++) s += s_gv[n2][i][kk] * Wt[kk];
    s_sc[n2][4+i] = s;
  }
  __syncthreads();

  if(t < 4){
    int d2 = dbase + t;
    int nz = nmask[d2];
    float q1=s_sc[t][0], q2=s_sc[t][1], q3=s_sc[t][2];
    float nrm = sqrtf(1.0f + q1*q1 + q2*q2 + q3*q3);
    float w=1.0f/nrm, x=q1/nrm, y=q2/nrm, z=q3/nrm;
    float Ru[3][3];
    Ru[0][0]=1.f-2.f*(y*y+z*z); Ru[0][1]=2.f*(x*y-w*z);     Ru[0][2]=2.f*(x*z+w*y);
    Ru[1][0]=2.f*(x*y+w*z);     Ru[1][1]=1.f-2.f*(x*x+z*z); Ru[1][2]=2.f*(y*z-w*x);
    Ru[2][0]=2.f*(x*z-w*y);     Ru[2][1]=2.f*(y*z+w*x);     Ru[2][2]=1.f-2.f*(x*x+y*y);
    for(int i=0;i<3;i++){
      for(int j=0;j<3;j++){
        float rv;
        if(nz){
          rv = rots[d2*9+i*3+0]*Ru[0][j] + rots[d2*9+i*3+1]*Ru[1][j] + rots[d2*9+i*3+2]*Ru[2][j];
        } else {
          rv = rots[d2*9+i*3+j];
        }
        out[OUT_ROT + d2*9 + i*3 + j] = rv;
      }
      float tv = trans[d2*3+i];
      out[OUT_TRANS + d2*3 + i] = nz ? (tv + s_sc[t][4+i]) : tv;
    }
  }
}

extern "C" void kernel_launch(void* const* d_in, const int* in_sizes, int n_in,
                              void* d_out, int out_size, void* d_ws, size_t ws_size,
                              hipStream_t stream)
{
  (void)in_sizes; (void)n_in; (void)out_size; (void)ws_size;
  const float* rots = (const float*)d_in[0];
  const float* trans = (const float*)d_in[1];
  const float* nf   = (const float*)d_in[2];
  const float* Wa1  = (const float*)d_in[3];
  const float* ba1  = (const float*)d_in[4];
  const float* Wa2  = (const float*)d_in[5];
  const float* Wv   = (const float*)d_in[6];
  const float* Wo   = (const float*)d_in[7];
  const float* Wg   = (const float*)d_in[8];
  const float* Wf1  = (const float*)d_in[9];
  const float* Wf2  = (const float*)d_in[10];
  const float* Wr1  = (const float*)d_in[11];
  const float* br1  = (const float*)d_in[12];
  const float* Wr2  = (const float*)d_in[13];
  const float* br2  = (const float*)d_in[14];
  const float* Wr3  = (const float*)d_in[15];
  const float* br3  = (const float*)d_in[16];
  const float* Wt   = (const float*)d_in[17];
  const int* xmask  = (const int*)d_in[19];
  const int* nmask  = (const int*)d_in[20];

  float* P = (float*)d_ws;                 // NN*1024 f32  (8 MB), layout [n][u][c]
  float* U = P + NN*1024;                  // NN*128       (1 MB)
  float* V = U + NN*128;                   // NN*128       (1 MB)
  int* srcs = (int*)(V + NN*128);          // NN*40 int    (320 KB)
  float* Y  = (float*)(srcs + NN*NFIX);    // NN*512 f32   (4 MB)
  float* Trel = Y + NN*512;                // 1023*128 f32 (0.52 MB)

  k_pretop<<<NN + 512 + 512, 256, 0, stream>>>(rots, trans, nf, Wa1, Wv,
                                               xmask, nmask, P, U, V, srcs, Trel);
  k_attn<<<NN, 256, 0, stream>>>(trans, Wa1, ba1, Wa2, Wo, U, V, P, Trel, srcs, Y);
  k_node<<<NN/4, 512, 0, stream>>>(rots, trans, Y, Wg, Wf1, Wf2,
                                   Wr1, br1, Wr2, br2, Wr3, br3, Wt,
                                   nmask, (float*)d_out);
}

// Round 12
// 138.951 us; speedup vs baseline: 1.2747x; 1.0061x over previous
//
#include <hip/hip_runtime.h>
#include <hip/hip_bf16.h>
#include <math.h>

#define NN 2048
#define CHAIN 512
#define KNN 30
#define LRK 10
#define NFIX 40
#define NSLOT 42
#define HPAD 132
#define NREL 1023

#define OUT_ROT 0
#define OUT_TRANS (NN*9)
#define OUT_BB (NN*9 + NN*3)

#define THREEFRY_PARTITIONABLE 1

__device__ __forceinline__ int xcd_swz(int b){ return ((b & 7) << 8) | (b >> 3); }

// ---------------- threefry2x32, key = (0, 42) ----------------
__device__ __forceinline__ unsigned rotl32(unsigned x, unsigned r){ return (x<<r)|(x>>(32u-r)); }

__device__ __forceinline__ void tf_block(unsigned &x0, unsigned &x1){
  const unsigned k0 = 0u, k1 = 42u, k2 = 0x1BD11BDAu ^ 0u ^ 42u;
  x0 += k0; x1 += k1;
#define TFR(a) x0 += x1; x1 = rotl32(x1,(a)); x1 ^= x0;
  TFR(13) TFR(15) TFR(26) TFR(6)   x0 += k1; x1 += k2 + 1u;
  TFR(17) TFR(29) TFR(16) TFR(24)  x0 += k2; x1 += k0 + 2u;
  TFR(13) TFR(15) TFR(26) TFR(6)   x0 += k0; x1 += k1 + 3u;
  TFR(17) TFR(29) TFR(16) TFR(24)  x0 += k1; x1 += k2 + 4u;
  TFR(13) TFR(15) TFR(26) TFR(6)   x0 += k2; x1 += k0 + 5u;
#undef TFR
}

__device__ __forceinline__ float gumbel_from_bits(unsigned bits){
  float f = __uint_as_float((bits >> 9) | 0x3f800000u) - 1.0f;
  const float tiny = 1.17549435e-38f;
  float u = fmaxf(tiny, f * (1.0f - tiny) + tiny);
  return -logf(-logf(u));
}

__device__ __forceinline__ float gumbel_at(unsigned p){
#if THREEFRY_PARTITIONABLE
  unsigned x0 = 0u, x1 = p;
  tf_block(x0, x1);
  return gumbel_from_bits(x0 ^ x1);
#else
  const unsigned HALF = (NN*(unsigned)NN)/2u;
  unsigned c0, c1; bool lo = p < HALF;
  if(lo){ c0 = p; c1 = p + HALF; } else { c0 = p - HALF; c1 = p; }
  tf_block(c0, c1);
  return gumbel_from_bits(lo ? c0 : c1);
#endif
}

// ---------------- K1: fused topk / prep / Trel (block-role split) ------------
__global__ __launch_bounds__(256) void k_pretop(
    const float* __restrict__ rots, const float* __restrict__ trans,
    const float* __restrict__ nf, const float* __restrict__ Wa1,
    const float* __restrict__ Wv,
    const int* __restrict__ xmask, const int* __restrict__ nmask,
    float* __restrict__ P, float* __restrict__ U, float* __restrict__ V,
    int* __restrict__ srcs, float* __restrict__ Trel)
{
  __shared__ __align__(16) char smem[4*4*132*4];
  int bb = blockIdx.x, t = threadIdx.x;

  if(bb >= NN + 512){
    // ---------------- Trel role ----------------
    int r = (bb - (NN+512))*2 + (t >> 7);
    int k = t & 127;
    if(r < NREL){
      float rel = (float)(r - 511);
      float acc = 0.f;
#pragma unroll
      for(int j=0;j<8;j++){
        float fr = expf((float)(2*j) * (float)(-0.5756462732485115));
        float ang = rel * fr;
        acc += cosf(ang) * Wa1[(278+j)*128 + k];
        acc += sinf(ang) * Wa1[(286+j)*128 + k];
      }
      Trel[r*128 + k] = acc;
    }
    return;
  }

  if(bb < NN){
    // ---------------- topk role ----------------
    unsigned* s_kk = (unsigned*)smem;          // [512]
    unsigned* s_lk = s_kk + CHAIN;             // [512]
    int i = bb;
    int base = (i >> 9) << 9;
    float tx = trans[i*3+0], ty = trans[i*3+1], tz = trans[i*3+2];
    for(int q=t; q<CHAIN; q+=256){
      int j = base + q;
      float dx = __fsub_rn(trans[j*3+0], tx);
      float dy = __fsub_rn(trans[j*3+1], ty);
      float dz = __fsub_rn(trans[j*3+2], tz);
      float d2 = __fadd_rn(__fadd_rn(__fmul_rn(dx,dx),__fmul_rn(dy,dy)),__fmul_rn(dz,dz));
      bool val = (j != i);
      float dm = val ? d2 : 1e30f;
      s_kk[q] = __float_as_uint(dm) ^ 0x80000000u;
      if(val){
        float g = gumbel_at((unsigned)(i*NN + j));
        float sc = __fadd_rn(__fmul_rn(-1.5f, logf(dm)), g);
        unsigned b = __float_as_uint(sc);
        unsigned ord = b ^ ((b & 0x80000000u) ? 0xFFFFFFFFu : 0x80000000u);
        s_lk[q] = ~ord;
      } else {
        s_lk[q] = 0xFFFFFFFFu;
      }
    }
    __syncthreads();
    if(t < 128){
      int w = t >> 6, lane = t & 63;
      unsigned* arr = w ? s_lk : s_kk;
      int K = w ? LRK : KNN;
      int outoff = w ? KNN : 0;
      unsigned long long k0_ = ((unsigned long long)arr[lane      ]<<32) | (unsigned)(lane);
      unsigned long long k1_ = ((unsigned long long)arr[lane + 64 ]<<32) | (unsigned)(lane+64);
      unsigned long long k2_ = ((unsigned long long)arr[lane + 128]<<32) | (unsigned)(lane+128);
      unsigned long long k3_ = ((unsigned long long)arr[lane + 192]<<32) | (unsigned)(lane+192);
      unsigned long long k4_ = ((unsigned long long)arr[lane + 256]<<32) | (unsigned)(lane+256);
      unsigned long long k5_ = ((unsigned long long)arr[lane + 320]<<32) | (unsigned)(lane+320);
      unsigned long long k6_ = ((unsigned long long)arr[lane + 384]<<32) | (unsigned)(lane+384);
      unsigned long long k7_ = ((unsigned long long)arr[lane + 448]<<32) | (unsigned)(lane+448);
      unsigned long long lmin;
      {
        unsigned long long a01 = k0_<k1_?k0_:k1_, a23 = k2_<k3_?k2_:k3_;
        unsigned long long a45 = k4_<k5_?k4_:k5_, a67 = k6_<k7_?k6_:k7_;
        unsigned long long a03 = a01<a23?a01:a23, a47 = a45<a67?a45:a67;
        lmin = a03<a47?a03:a47;
      }
      for(int k=0;k<K;k++){
        unsigned long long r = lmin;
        for(int off=32; off; off>>=1){
          unsigned long long o = __shfl_xor(r, off, 64);
          if(o < r) r = o;
        }
        if(lane == 0) srcs[i*NFIX + outoff + k] = base + (int)(unsigned)(r & 0xffffffffull);
        if(r == lmin){
          if(k0_ == r) k0_ = ~0ull;
          if(k1_ == r) k1_ = ~0ull;
          if(k2_ == r) k2_ = ~0ull;
          if(k3_ == r) k3_ = ~0ull;
          if(k4_ == r) k4_ = ~0ull;
          if(k5_ == r) k5_ = ~0ull;
          if(k6_ == r) k6_ = ~0ull;
          if(k7_ == r) k7_ = ~0ull;
          unsigned long long a01 = k0_<k1_?k0_:k1_, a23 = k2_<k3_?k2_:k3_;
          unsigned long long a45 = k4_<k5_?k4_:k5_, a67 = k6_<k7_?k6_:k7_;
          unsigned long long a03 = a01<a23?a01:a23, a47 = a45<a67?a45:a67;
          lmin = a03<a47?a03:a47;
        }
      }
    }
    return;
  }

  // ---------------- prep role (4 nodes) ----------------
  float (*fr)[4][132] = (float (*)[4][132])smem;
  int n0 = (bb - NN)*4;
  for(int i=t; i<2048; i+=256){
    int nd = i>>9, c = (i>>7)&3, kk = i&127;
    fr[nd][c][kk] = nf[(n0+nd)*512 + c*128 + kk];
  }
  if(t < 4){
    fr[t][0][128] = 0.0f; fr[t][0][129] = 0.0f;
    fr[t][0][130] = (nmask[n0+t] != 0 && xmask[n0+t] == 0) ? 1.0f : 0.0f;
  } else if(t >= 16 && t < 52){
    int q = t - 16; int nd = q/9, r = q%9, a = r/3, i = r%3;
    int n = n0 + nd;
    const float BB[3][3] = {{-0.525f,1.363f,0.0f},{0.f,0.f,0.f},{1.526f,0.f,0.f}};
    float bb_ = rots[n*9+i*3+0]*BB[a][0] + rots[n*9+i*3+1]*BB[a][1]
              + rots[n*9+i*3+2]*BB[a][2] + trans[n*3+i];
    fr[nd][1+i][128+a] = bb_;
  }
  __syncthreads();

  float a[4][4];
#pragma unroll
  for(int nd=0;nd<4;nd++)
#pragma unroll
    for(int c=0;c<4;c++) a[nd][c]=0.f;
  for(int j=0;j<128;j+=4){
    float w0=Wv[(j+0)*256+t], w1=Wv[(j+1)*256+t], w2=Wv[(j+2)*256+t], w3=Wv[(j+3)*256+t];
#pragma unroll
    for(int nd=0;nd<4;nd++){
#pragma unroll
      for(int c=0;c<4;c++){
        float4 f4 = *(const float4*)&fr[nd][c][j];
        a[nd][c] += f4.x*w0 + f4.y*w1 + f4.z*w2 + f4.w*w3;
      }
    }
  }
  for(int j=128;j<131;j++){
    float w = Wv[j*256+t];
#pragma unroll
    for(int nd=0;nd<4;nd++)
#pragma unroll
      for(int c=0;c<4;c++) a[nd][c] += fr[nd][c][j]*w;
  }
#pragma unroll
  for(int nd=0;nd<4;nd++){
    float4 v4; v4.x=a[nd][0]; v4.y=a[nd][1]; v4.z=a[nd][2]; v4.w=a[nd][3];
    *(float4*)&P[(n0+nd)*1024 + t*4] = v4;   // layout [n][u][c]
  }

  int k = t & 127;
  int isV = t >> 7;
  const float* Wcol = Wa1 + (isV ? 131*128 : 0);
  float u[4] = {0.f,0.f,0.f,0.f};
  for(int j=0;j<128;j+=4){
    float w0=Wcol[(j+0)*128+k], w1=Wcol[(j+1)*128+k], w2=Wcol[(j+2)*128+k], w3=Wcol[(j+3)*128+k];
#pragma unroll
    for(int nd=0;nd<4;nd++){
      float4 f4 = *(const float4*)&fr[nd][0][j];
      u[nd] += f4.x*w0 + f4.y*w1 + f4.z*w2 + f4.w*w3;
    }
  }
  for(int j=128;j<131;j++){
    float w = Wcol[j*128+k];
#pragma unroll
    for(int nd=0;nd<4;nd++) u[nd] += fr[nd][0][j]*w;
  }
  float* OUT = isV ? V : U;
#pragma unroll
  for(int nd=0;nd<4;nd++) OUT[(n0+nd)*128 + k] = u[nd];
}

// ---------------- K3: edge logits + softmax + agg + @Wo (stage5/6 restructured) ----
__global__ __launch_bounds__(256) void k_attn(
    const float* __restrict__ trans, const float* __restrict__ Wa1,
    const float* __restrict__ ba1, const float* __restrict__ Wa2,
    const float* __restrict__ Wo,
    const float* __restrict__ U, const float* __restrict__ V,
    const float* __restrict__ P, const float* __restrict__ Trel,
    const int* __restrict__ srcs, float* __restrict__ Y)
{
  __shared__ int   s_src[NSLOT];
  __shared__ int   s_val[NSLOT];
  __shared__ float s_dist[NSLOT];
  __shared__ __align__(16) float s_H[NSLOT*HPAD];   // 22176 B (also: stage6 partials [2][4][128])
  __shared__ __align__(16) float s_mux[NSLOT*32];   // 5376 B: rbf | wa2t | agg4[256][4]
  __shared__ float s_att[NSLOT*8];

  int b = blockIdx.x, t = threadIdx.x;
  int d = xcd_swz(b);
  int pos = d & (CHAIN-1);
  int k = t & 127, grp = t >> 7;

  if(t < NSLOT){
    int src;
    if(t < NFIX)      src = srcs[d*NFIX + t];
    else if(t == NFIX) src = (pos > 0)       ? d-1 : d;
    else               src = (pos < CHAIN-1) ? d+1 : d;
    s_src[t] = src;
    float dx = trans[src*3+0]-trans[d*3+0];
    float dy = trans[src*3+1]-trans[d*3+1];
    float dz = trans[src*3+2]-trans[d*3+2];
    float dist = sqrtf(dx*dx + dy*dy + dz*dz + 1e-12f);
    s_dist[t] = dist;
    s_val[t] = (dist > 1e-3f) ? 1 : 0;
  }

  float wreg[16];
#pragma unroll
  for(int f=0; f<16; f++) wreg[f] = Wa1[(262+f)*128 + k];
  float ubias = ba1[k] + V[d*128 + k];
  __syncthreads();

  // stage 1: rbf[42][16]
  for(int i=t; i<NSLOT*16; i+=256){
    int e = i >> 4, f = i & 15;
    float zz = (s_dist[e] - (float)f * (20.0f/15.0f)) * 0.8f;
    s_mux[i] = expf(-(zz*zz));
  }
  __syncthreads();

  // stage 2a: gather U[src]+Trel[rel] -> s_H
  for(int e = grp; e < NSLOT; e += 2){
    int src = s_src[e];
    s_H[e*HPAD + k] = U[src*128 + k] + Trel[(src - d + 511)*128 + k];
  }
  // stage 2b: H = leaky(ubias + gathered + rbf.wreg)
  for(int e = grp; e < NSLOT; e += 2){
    float h = ubias + s_H[e*HPAD + k];
    const float4* rp = (const float4*)(s_mux + e*16);
#pragma unroll
    for(int q=0; q<4; q++){
      float4 ev = rp[q];
      h += ev.x*wreg[4*q+0] + ev.y*wreg[4*q+1] + ev.z*wreg[4*q+2] + ev.w*wreg[4*q+3];
    }
    h = (h >= 0.0f) ? h : 0.01f*h;
    s_H[e*HPAD + k] = h;
  }
  __syncthreads();

  // stage 2.5: Wa2^T -> s_mux (rbf dead)
  for(int i=t; i<1024; i+=256){
    int kk = i >> 3, h = i & 7;
    s_mux[h*HPAD + kk] = Wa2[i];
  }
  __syncthreads();

  // stage 3: logits[e][h] = H[e] . Wa2[:,h]
  for(int p = t; p < NSLOT*8; p += 256){
    int e = p >> 3, h = p & 7;
    const float4* Hp = (const float4*)(s_H + e*HPAD);
    const float4* Wp = (const float4*)(s_mux + h*HPAD);
    float acc = 0.f;
#pragma unroll
    for(int q=0; q<32; q++){
      float4 a = Hp[q], w = Wp[q];
      acc += a.x*w.x + a.y*w.y + a.z*w.z + a.w*w.w;
    }
    s_att[p] = s_val[e] ? acc : -1e30f;
  }
  __syncthreads();

  // stage 4: per-head softmax
  if(t < 64){
    int h = t & 7, g = t >> 3;
    float m = -INFINITY;
    for(int e=g; e<NSLOT; e+=8) m = fmaxf(m, s_att[e*8+h]);
    for(int off=8; off<64; off<<=1) m = fmaxf(m, __shfl_xor(m, off, 64));
    m = (m > -5e29f) ? m : 0.0f;
    float z = 0.0f;
    for(int e=g; e<NSLOT; e+=8){
      float p = expf(s_att[e*8+h] - m);
      s_att[e*8+h] = p; z += p;
    }
    for(int off=8; off<64; off<<=1) z += __shfl_xor(z, off, 64);
    float inv = 1.0f / (z + 1e-9f);
    for(int e=g; e<NSLOT; e+=8) s_att[e*8+h] *= inv;
  }
  __syncthreads();

  // stage 5: agg4[u=t] = float4 over c (one ds_write_b128)
  {
    int h = t >> 5;
    float a0=0.f,a1=0.f,a2=0.f,a3=0.f;
    for(int e=0;e<NSLOT;e++){
      float w = s_att[e*8 + h];
      float4 p4 = *(const float4*)(P + (size_t)s_src[e]*1024 + t*4);
      a0 += w*p4.x; a1 += w*p4.y; a2 += w*p4.z; a3 += w*p4.w;
    }
    float4 av; av.x=a0; av.y=a1; av.z=a2; av.w=a3;
    *(float4*)&s_mux[t*4] = av;   // agg4[u][c], u=t
  }
  __syncthreads();

  // stage 6a: half-split partials: thread (half=grp, k) sums its u-range for ALL 4 c.
  // Each Wo element is loaded exactly once per block (coalesced across k).
  {
    const float* WoB = Wo + (grp*128)*128 + k;
    const float4* ag = (const float4*)(s_mux) + grp*128;
    float x0=0.f,x1=0.f,x2=0.f,x3=0.f;
#pragma unroll 4
    for(int uu=0; uu<128; uu++){
      float w = WoB[uu*128];
      float4 av = ag[uu];            // broadcast (uniform address per wave)
      x0 += av.x*w; x1 += av.y*w; x2 += av.z*w; x3 += av.w*w;
    }
    float* part = s_H;               // dead since stage 3; [half][c*128+k]
    part[grp*512 + 0*128 + k] = x0;
    part[grp*512 + 1*128 + k] = x1;
    part[grp*512 + 2*128 + k] = x2;
    part[grp*512 + 3*128 + k] = x3;
  }
  __syncthreads();

  // stage 6b: final reduction + store (coalesced)
  {
    float y0 = s_H[t]       + s_H[512 + t];
    float y1 = s_H[256 + t] + s_H[512 + 256 + t];
    Y[d*512 + t]       = y0;
    Y[d*512 + 256 + t] = y1;
  }
}

// ---------------- K5: per-node MLP chain, 4 nodes/block, 512 threads ------------
__global__ __launch_bounds__(512) void k_node(
    const float* __restrict__ rots, const float* __restrict__ trans,
    const float* __restrict__ Y,
    const float* __restrict__ Wg, const float* __restrict__ Wf1,
    const float* __restrict__ Wf2, const float* __restrict__ Wr1,
    const float* __restrict__ br1, const float* __restrict__ Wr2,
    const float* __restrict__ br2, const float* __restrict__ Wr3,
    const float* __restrict__ br3, const float* __restrict__ Wt,
    const int* __restrict__ nmask, float* __restrict__ out)
{
  __shared__ __align__(16) float s_y[4][4][128];
  __shared__ __align__(16) float s_t1[4][128];
  __shared__ __align__(16) float s_bb0[4][128];
  __shared__ __align__(16) float s_gv[4][3][128];
  __shared__ __align__(16) float s_h1[4][256];
  __shared__ __align__(16) float s_h2[4][128];
  __shared__ float s_sc[4][8];

  int b = blockIdx.x, t = threadIdx.x;
  int nd = t >> 7, k = t & 127;
  int dbase = b*4;
  int d = dbase + nd;
  for(int i=t; i<4*512; i+=512){
    int n2 = i>>9, c=(i>>7)&3, kk=i&127;
    s_y[n2][c][kk] = Y[(dbase+n2)*512 + c*128 + kk];
  }
  __syncthreads();

  float g=0.f, f1=0.f;
  for(int j=0;j<128;j+=4){
    float wg0=Wg[(j+0)*128+k], wg1=Wg[(j+1)*128+k], wg2=Wg[(j+2)*128+k], wg3=Wg[(j+3)*128+k];
    float wf0=Wf1[(j+0)*128+k], wf1_=Wf1[(j+1)*128+k], wf2_=Wf1[(j+2)*128+k], wf3=Wf1[(j+3)*128+k];
    float4 yv = *(const float4*)&s_y[nd][0][j];
    g  += yv.x*wg0 + yv.y*wg1 + yv.z*wg2 + yv.w*wg3;
    f1 += yv.x*wf0 + yv.y*wf1_ + yv.z*wf2_ + yv.w*wf3;
  }
  float gate = 1.0f/(1.0f + expf(-g));
  s_t1[nd][k] = fmaxf(f1, 0.0f);
  __syncthreads();

  float f0=0.f;
  for(int j=0;j<128;j+=4){
    float w0=Wf2[(j+0)*128+k], w1=Wf2[(j+1)*128+k], w2=Wf2[(j+2)*128+k], w3=Wf2[(j+3)*128+k];
    float4 tv = *(const float4*)&s_t1[nd][j];
    f0 += tv.x*w0 + tv.y*w1 + tv.z*w2 + tv.w*w3;
  }
  {
    float bb0 = s_y[nd][0][k] + f0;
    s_bb0[nd][k] = bb0;
    out[OUT_BB + d*512 + k] = bb0;
#pragma unroll
    for(int c=1;c<4;c++){
      float v = s_y[nd][c][k] * gate;
      s_gv[nd][c-1][k] = v;
      out[OUT_BB + d*512 + c*128 + k] = v;
    }
  }
  __syncthreads();

  float a1 = br1[k], a2 = br1[128+k];
  for(int j=0;j<128;j+=4){
    float w10=Wr1[(j+0)*256+k],     w11=Wr1[(j+1)*256+k],     w12=Wr1[(j+2)*256+k],     w13=Wr1[(j+3)*256+k];
    float w20=Wr1[(j+0)*256+128+k], w21=Wr1[(j+1)*256+128+k], w22=Wr1[(j+2)*256+128+k], w23=Wr1[(j+3)*256+128+k];
    float4 bv = *(const float4*)&s_bb0[nd][j];
    a1 += bv.x*w10 + bv.y*w11 + bv.z*w12 + bv.w*w13;
    a2 += bv.x*w20 + bv.y*w21 + bv.z*w22 + bv.w*w23;
  }
  s_h1[nd][k] = fmaxf(a1, 0.0f);
  s_h1[nd][128+k] = fmaxf(a2, 0.0f);
  __syncthreads();

  float a = br2[k];
  for(int j=0;j<256;j+=4){
    float w0=Wr2[(j+0)*128+k], w1=Wr2[(j+1)*128+k], w2=Wr2[(j+2)*128+k], w3=Wr2[(j+3)*128+k];
    float4 hv = *(const float4*)&s_h1[nd][j];
    a += hv.x*w0 + hv.y*w1 + hv.z*w2 + hv.w*w3;
  }
  s_h2[nd][k] = fmaxf(a, 0.0f);
  __syncthreads();

  if(t < 12){
    int n2 = t/3, r = t%3;
    float q = br3[r];
    for(int kk=0;kk<128;kk++) q += s_h2[n2][kk] * Wr3[kk*6 + r];
    s_sc[n2][r] = q;
  } else if(t >= 32 && t < 44){
    int q2 = t-32; int n2 = q2/3, i = q2%3;
    float s = 0.f;
    for(int kk=0;kk<128;kk++) s += s_gv[n2][i][kk] * Wt[kk];
    s_sc[n2][4+i] = s;
  }
  __syncthreads();

  if(t < 4){
    int d2 = dbase + t;
    int nz = nmask[d2];
    float q1=s_sc[t][0], q2=s_sc[t][1], q3=s_sc[t][2];
    float nrm = sqrtf(1.0f + q1*q1 + q2*q2 + q3*q3);
    float w=1.0f/nrm, x=q1/nrm, y=q2/nrm, z=q3/nrm;
    float Ru[3][3];
    Ru[0][0]=1.f-2.f*(y*y+z*z); Ru[0][1]=2.f*(x*y-w*z);     Ru[0][2]=2.f*(x*z+w*y);
    Ru[1][0]=2.f*(x*y+w*z);     Ru[1][1]=1.f-2.f*(x*x+z*z); Ru[1][2]=2.f*(y*z-w*x);
    Ru[2][0]=2.f*(x*z-w*y);     Ru[2][1]=2.f*(y*z+w*x);     Ru[2][2]=1.f-2.f*(x*x+y*y);
    for(int i=0;i<3;i++){
      for(int j=0;j<3;j++){
        float rv;
        if(nz){
          rv = rots[d2*9+i*3+0]*Ru[0][j] + rots[d2*9+i*3+1]*Ru[1][j] + rots[d2*9+i*3+2]*Ru[2][j];
        } else {
          rv = rots[d2*9+i*3+j];
        }
        out[OUT_ROT + d2*9 + i*3 + j] = rv;
      }
      float tv = trans[d2*3+i];
      out[OUT_TRANS + d2*3 + i] = nz ? (tv + s_sc[t][4+i]) : tv;
    }
  }
}

extern "C" void kernel_launch(void* const* d_in, const int* in_sizes, int n_in,
                              void* d_out, int out_size, void* d_ws, size_t ws_size,
                              hipStream_t stream)
{
  (void)in_sizes; (void)n_in; (void)out_size; (void)ws_size;
  const float* rots = (const float*)d_in[0];
  const float* trans = (const float*)d_in[1];
  const float* nf   = (const float*)d_in[2];
  const float* Wa1  = (const float*)d_in[3];
  const float* ba1  = (const float*)d_in[4];
  const float* Wa2  = (const float*)d_in[5];
  const float* Wv   = (const float*)d_in[6];
  const float* Wo   = (const float*)d_in[7];
  const float* Wg   = (const float*)d_in[8];
  const float* Wf1  = (const float*)d_in[9];
  const float* Wf2  = (const float*)d_in[10];
  const float* Wr1  = (const float*)d_in[11];
  const float* br1  = (const float*)d_in[12];
  const float* Wr2  = (const float*)d_in[13];
  const float* br2  = (const float*)d_in[14];
  const float* Wr3  = (const float*)d_in[15];
  const float* br3  = (const float*)d_in[16];
  const float* Wt   = (const float*)d_in[17];
  const int* xmask  = (const int*)d_in[19];
  const int* nmask  = (const int*)d_in[20];

  float* P = (float*)d_ws;                 // NN*1024 f32  (8 MB), layout [n][u][c]
  float* U = P + NN*1024;                  // NN*128       (1 MB)
  float* V = U + NN*128;                   // NN*128       (1 MB)
  int* srcs = (int*)(V + NN*128);          // NN*40 int    (320 KB)
  float* Y  = (float*)(srcs + NN*NFIX);    // NN*512 f32   (4 MB)
  float* Trel = Y + NN*512;                // 1023*128 f32 (0.52 MB)

  k_pretop<<<NN + 512 + 512, 256, 0, stream>>>(rots, trans, nf, Wa1, Wv,
                                               xmask, nmask, P, U, V, srcs, Trel);
  k_attn<<<NN, 256, 0, stream>>>(trans, Wa1, ba1, Wa2, Wo, U, V, P, Trel, srcs, Y);
  k_node<<<NN/4, 512, 0, stream>>>(rots, trans, Y, Wg, Wf1, Wf2,
                                   Wr1, br1, Wr2, br2, Wr3, br3, Wt,
                                   nmask, (float*)d_out);
}

// Round 13
// 138.423 us; speedup vs baseline: 1.2795x; 1.0038x over previous
//
#include <hip/hip_runtime.h>
#include <hip/hip_bf16.h>
#include <math.h>

#define NN 2048
#define CHAIN 512
#define KNN 30
#define LRK 10
#define NFIX 40
#define NSLOT 42
#define HPAD 132
#define AGPAD 260
#define NREL 1023

#define OUT_ROT 0
#define OUT_TRANS (NN*9)
#define OUT_BB (NN*9 + NN*3)

#define THREEFRY_PARTITIONABLE 1

__device__ __forceinline__ int xcd_swz(int b){ return ((b & 7) << 8) | (b >> 3); }

// ---------------- threefry2x32, key = (0, 42) ----------------
__device__ __forceinline__ unsigned rotl32(unsigned x, unsigned r){ return (x<<r)|(x>>(32u-r)); }

__device__ __forceinline__ void tf_block(unsigned &x0, unsigned &x1){
  const unsigned k0 = 0u, k1 = 42u, k2 = 0x1BD11BDAu ^ 0u ^ 42u;
  x0 += k0; x1 += k1;
#define TFR(a) x0 += x1; x1 = rotl32(x1,(a)); x1 ^= x0;
  TFR(13) TFR(15) TFR(26) TFR(6)   x0 += k1; x1 += k2 + 1u;
  TFR(17) TFR(29) TFR(16) TFR(24)  x0 += k2; x1 += k0 + 2u;
  TFR(13) TFR(15) TFR(26) TFR(6)   x0 += k0; x1 += k1 + 3u;
  TFR(17) TFR(29) TFR(16) TFR(24)  x0 += k1; x1 += k2 + 4u;
  TFR(13) TFR(15) TFR(26) TFR(6)   x0 += k2; x1 += k0 + 5u;
#undef TFR
}

__device__ __forceinline__ float gumbel_from_bits(unsigned bits){
  float f = __uint_as_float((bits >> 9) | 0x3f800000u) - 1.0f;
  const float tiny = 1.17549435e-38f;
  float u = fmaxf(tiny, f * (1.0f - tiny) + tiny);
  return -logf(-logf(u));
}

__device__ __forceinline__ float gumbel_at(unsigned p){
#if THREEFRY_PARTITIONABLE
  unsigned x0 = 0u, x1 = p;
  tf_block(x0, x1);
  return gumbel_from_bits(x0 ^ x1);
#else
  const unsigned HALF = (NN*(unsigned)NN)/2u;
  unsigned c0, c1; bool lo = p < HALF;
  if(lo){ c0 = p; c1 = p + HALF; } else { c0 = p - HALF; c1 = p; }
  tf_block(c0, c1);
  return gumbel_from_bits(lo ? c0 : c1);
#endif
}

// ---------------- K1: fused topk / prep / Trel (block-role split) ------------
__global__ __launch_bounds__(256) void k_pretop(
    const float* __restrict__ rots, const float* __restrict__ trans,
    const float* __restrict__ nf, const float* __restrict__ Wa1,
    const float* __restrict__ Wv,
    const int* __restrict__ xmask, const int* __restrict__ nmask,
    float* __restrict__ P, float* __restrict__ U, float* __restrict__ V,
    int* __restrict__ srcs, float* __restrict__ Trel)
{
  __shared__ __align__(16) char smem[4*4*132*4];
  int bb = blockIdx.x, t = threadIdx.x;

  if(bb >= NN + 512){
    // ---------------- Trel role ----------------
    int r = (bb - (NN+512))*2 + (t >> 7);
    int k = t & 127;
    if(r < NREL){
      float rel = (float)(r - 511);
      float acc = 0.f;
#pragma unroll
      for(int j=0;j<8;j++){
        float fr = expf((float)(2*j) * (float)(-0.5756462732485115));
        float ang = rel * fr;
        acc += cosf(ang) * Wa1[(278+j)*128 + k];
        acc += sinf(ang) * Wa1[(286+j)*128 + k];
      }
      Trel[r*128 + k] = acc;
    }
    return;
  }

  if(bb < NN){
    // ---------------- topk role ----------------
    unsigned* s_kk = (unsigned*)smem;          // [512]
    unsigned* s_lk = s_kk + CHAIN;             // [512]
    int i = bb;
    int base = (i >> 9) << 9;
    float tx = trans[i*3+0], ty = trans[i*3+1], tz = trans[i*3+2];
    for(int q=t; q<CHAIN; q+=256){
      int j = base + q;
      float dx = __fsub_rn(trans[j*3+0], tx);
      float dy = __fsub_rn(trans[j*3+1], ty);
      float dz = __fsub_rn(trans[j*3+2], tz);
      float d2 = __fadd_rn(__fadd_rn(__fmul_rn(dx,dx),__fmul_rn(dy,dy)),__fmul_rn(dz,dz));
      bool val = (j != i);
      float dm = val ? d2 : 1e30f;
      s_kk[q] = __float_as_uint(dm) ^ 0x80000000u;
      if(val){
        float g = gumbel_at((unsigned)(i*NN + j));
        float sc = __fadd_rn(__fmul_rn(-1.5f, logf(dm)), g);
        unsigned b = __float_as_uint(sc);
        unsigned ord = b ^ ((b & 0x80000000u) ? 0xFFFFFFFFu : 0x80000000u);
        s_lk[q] = ~ord;
      } else {
        s_lk[q] = 0xFFFFFFFFu;
      }
    }
    __syncthreads();
    if(t < 128){
      int w = t >> 6, lane = t & 63;
      unsigned* arr = w ? s_lk : s_kk;
      int K = w ? LRK : KNN;
      int outoff = w ? KNN : 0;
      unsigned long long k0_ = ((unsigned long long)arr[lane      ]<<32) | (unsigned)(lane);
      unsigned long long k1_ = ((unsigned long long)arr[lane + 64 ]<<32) | (unsigned)(lane+64);
      unsigned long long k2_ = ((unsigned long long)arr[lane + 128]<<32) | (unsigned)(lane+128);
      unsigned long long k3_ = ((unsigned long long)arr[lane + 192]<<32) | (unsigned)(lane+192);
      unsigned long long k4_ = ((unsigned long long)arr[lane + 256]<<32) | (unsigned)(lane+256);
      unsigned long long k5_ = ((unsigned long long)arr[lane + 320]<<32) | (unsigned)(lane+320);
      unsigned long long k6_ = ((unsigned long long)arr[lane + 384]<<32) | (unsigned)(lane+384);
      unsigned long long k7_ = ((unsigned long long)arr[lane + 448]<<32) | (unsigned)(lane+448);
      unsigned long long lmin;
      {
        unsigned long long a01 = k0_<k1_?k0_:k1_, a23 = k2_<k3_?k2_:k3_;
        unsigned long long a45 = k4_<k5_?k4_:k5_, a67 = k6_<k7_?k6_:k7_;
        unsigned long long a03 = a01<a23?a01:a23, a47 = a45<a67?a45:a67;
        lmin = a03<a47?a03:a47;
      }
      for(int k=0;k<K;k++){
        unsigned long long r = lmin;
        for(int off=32; off; off>>=1){
          unsigned long long o = __shfl_xor(r, off, 64);
          if(o < r) r = o;
        }
        if(lane == 0) srcs[i*NFIX + outoff + k] = base + (int)(unsigned)(r & 0xffffffffull);
        if(r == lmin){
          if(k0_ == r) k0_ = ~0ull;
          if(k1_ == r) k1_ = ~0ull;
          if(k2_ == r) k2_ = ~0ull;
          if(k3_ == r) k3_ = ~0ull;
          if(k4_ == r) k4_ = ~0ull;
          if(k5_ == r) k5_ = ~0ull;
          if(k6_ == r) k6_ = ~0ull;
          if(k7_ == r) k7_ = ~0ull;
          unsigned long long a01 = k0_<k1_?k0_:k1_, a23 = k2_<k3_?k2_:k3_;
          unsigned long long a45 = k4_<k5_?k4_:k5_, a67 = k6_<k7_?k6_:k7_;
          unsigned long long a03 = a01<a23?a01:a23, a47 = a45<a67?a45:a67;
          lmin = a03<a47?a03:a47;
        }
      }
    }
    return;
  }

  // ---------------- prep role (4 nodes) ----------------
  float (*fr)[4][132] = (float (*)[4][132])smem;
  int n0 = (bb - NN)*4;
  for(int i=t; i<2048; i+=256){
    int nd = i>>9, c = (i>>7)&3, kk = i&127;
    fr[nd][c][kk] = nf[(n0+nd)*512 + c*128 + kk];
  }
  if(t < 4){
    fr[t][0][128] = 0.0f; fr[t][0][129] = 0.0f;
    fr[t][0][130] = (nmask[n0+t] != 0 && xmask[n0+t] == 0) ? 1.0f : 0.0f;
  } else if(t >= 16 && t < 52){
    int q = t - 16; int nd = q/9, r = q%9, a = r/3, i = r%3;
    int n = n0 + nd;
    const float BB[3][3] = {{-0.525f,1.363f,0.0f},{0.f,0.f,0.f},{1.526f,0.f,0.f}};
    float bb_ = rots[n*9+i*3+0]*BB[a][0] + rots[n*9+i*3+1]*BB[a][1]
              + rots[n*9+i*3+2]*BB[a][2] + trans[n*3+i];
    fr[nd][1+i][128+a] = bb_;
  }
  __syncthreads();

  float a[4][4];
#pragma unroll
  for(int nd=0;nd<4;nd++)
#pragma unroll
    for(int c=0;c<4;c++) a[nd][c]=0.f;
  for(int j=0;j<128;j+=4){
    float w0=Wv[(j+0)*256+t], w1=Wv[(j+1)*256+t], w2=Wv[(j+2)*256+t], w3=Wv[(j+3)*256+t];
#pragma unroll
    for(int nd=0;nd<4;nd++){
#pragma unroll
      for(int c=0;c<4;c++){
        float4 f4 = *(const float4*)&fr[nd][c][j];
        a[nd][c] += f4.x*w0 + f4.y*w1 + f4.z*w2 + f4.w*w3;
      }
    }
  }
  for(int j=128;j<131;j++){
    float w = Wv[j*256+t];
#pragma unroll
    for(int nd=0;nd<4;nd++)
#pragma unroll
      for(int c=0;c<4;c++) a[nd][c] += fr[nd][c][j]*w;
  }
#pragma unroll
  for(int nd=0;nd<4;nd++){
    float4 v4; v4.x=a[nd][0]; v4.y=a[nd][1]; v4.z=a[nd][2]; v4.w=a[nd][3];
    *(float4*)&P[(n0+nd)*1024 + t*4] = v4;   // layout [n][u][c]
  }

  int k = t & 127;
  int isV = t >> 7;
  const float* Wcol = Wa1 + (isV ? 131*128 : 0);
  float u[4] = {0.f,0.f,0.f,0.f};
  for(int j=0;j<128;j+=4){
    float w0=Wcol[(j+0)*128+k], w1=Wcol[(j+1)*128+k], w2=Wcol[(j+2)*128+k], w3=Wcol[(j+3)*128+k];
#pragma unroll
    for(int nd=0;nd<4;nd++){
      float4 f4 = *(const float4*)&fr[nd][0][j];
      u[nd] += f4.x*w0 + f4.y*w1 + f4.z*w2 + f4.w*w3;
    }
  }
  for(int j=128;j<131;j++){
    float w = Wcol[j*128+k];
#pragma unroll
    for(int nd=0;nd<4;nd++) u[nd] += fr[nd][0][j]*w;
  }
  float* OUT = isV ? V : U;
#pragma unroll
  for(int nd=0;nd<4;nd++) OUT[(n0+nd)*128 + k] = u[nd];
}

// ---------------- K3: edge logits + softmax + agg + @Wo — 6-barrier schedule ----
// s_mux layout (1728 floats): [0,672) rbf -> later agg[4][260]; [672,1728) Wa2^T rows h*132
__global__ __launch_bounds__(256) void k_attn(
    const float* __restrict__ trans, const float* __restrict__ Wa1,
    const float* __restrict__ ba1, const float* __restrict__ Wa2,
    const float* __restrict__ Wo,
    const float* __restrict__ U, const float* __restrict__ V,
    const float* __restrict__ P, const float* __restrict__ Trel,
    const int* __restrict__ srcs, float* __restrict__ Y)
{
  __shared__ int   s_src[NSLOT];
  __shared__ int   s_val[NSLOT];
  __shared__ float s_dist[NSLOT];
  __shared__ __align__(16) float s_H[NSLOT*HPAD];   // 22176 B
  __shared__ __align__(16) float s_mux[1728];       // 6912 B
  __shared__ float s_att[NSLOT*8];

  int b = blockIdx.x, t = threadIdx.x;
  int d = xcd_swz(b);
  int pos = d & (CHAIN-1);
  int k = t & 127, grp = t >> 7;

  // ---- phase 0 (pre-sync1): edge meta + Wa2^T staging + per-thread reg loads ----
  if(t < NSLOT){
    int src;
    if(t < NFIX)      src = srcs[d*NFIX + t];
    else if(t == NFIX) src = (pos > 0)       ? d-1 : d;
    else               src = (pos < CHAIN-1) ? d+1 : d;
    s_src[t] = src;
    float dx = trans[src*3+0]-trans[d*3+0];
    float dy = trans[src*3+1]-trans[d*3+1];
    float dz = trans[src*3+2]-trans[d*3+2];
    float dist = sqrtf(dx*dx + dy*dy + dz*dz + 1e-12f);
    s_dist[t] = dist;
    s_val[t] = (dist > 1e-3f) ? 1 : 0;
  }
  for(int i=t; i<1024; i+=256){          // Wa2^T: depends on nothing in-kernel
    int kk = i >> 3, h = i & 7;
    s_mux[672 + h*HPAD + kk] = Wa2[i];
  }
  float wreg[16];
#pragma unroll
  for(int f=0; f<16; f++) wreg[f] = Wa1[(262+f)*128 + k];
  float ubias = ba1[k] + V[d*128 + k];
  __syncthreads();                        // sync1

  // ---- phase 1: gather U/Trel (42 global loads in flight) + rbf transcendentals ----
  for(int e = grp; e < NSLOT; e += 2){
    int src = s_src[e];
    s_H[e*HPAD + k] = U[src*128 + k] + Trel[(src - d + 511)*128 + k];
  }
  for(int i=t; i<NSLOT*16; i+=256){
    int e = i >> 4, f = i & 15;
    float zz = (s_dist[e] - (float)f * (20.0f/15.0f)) * 0.8f;
    s_mux[i] = expf(-(zz*zz));
  }
  __syncthreads();                        // sync2

  // ---- phase 2: H = leaky(ubias + gathered + rbf.wreg) ----
  for(int e = grp; e < NSLOT; e += 2){
    float h = ubias + s_H[e*HPAD + k];
    const float4* rp = (const float4*)(s_mux + e*16);
#pragma unroll
    for(int q=0; q<4; q++){
      float4 ev = rp[q];
      h += ev.x*wreg[4*q+0] + ev.y*wreg[4*q+1] + ev.z*wreg[4*q+2] + ev.w*wreg[4*q+3];
    }
    h = (h >= 0.0f) ? h : 0.01f*h;
    s_H[e*HPAD + k] = h;
  }
  __syncthreads();                        // sync3

  // ---- phase 3: logits[e][h] = H[e] . Wa2[:,h] ----
  for(int p = t; p < NSLOT*8; p += 256){
    int e = p >> 3, h = p & 7;
    const float4* Hp = (const float4*)(s_H + e*HPAD);
    const float4* Wp = (const float4*)(s_mux + 672 + h*HPAD);
    float acc = 0.f;
#pragma unroll
    for(int q=0; q<32; q++){
      float4 a = Hp[q], w = Wp[q];
      acc += a.x*w.x + a.y*w.y + a.z*w.z + a.w*w.w;
    }
    s_att[p] = s_val[e] ? acc : -1e30f;
  }
  __syncthreads();                        // sync4

  // ---- phase 4: per-head softmax ----
  if(t < 64){
    int h = t & 7, g = t >> 3;
    float m = -INFINITY;
    for(int e=g; e<NSLOT; e+=8) m = fmaxf(m, s_att[e*8+h]);
    for(int off=8; off<64; off<<=1) m = fmaxf(m, __shfl_xor(m, off, 64));
    m = (m > -5e29f) ? m : 0.0f;
    float z = 0.0f;
    for(int e=g; e<NSLOT; e+=8){
      float p = expf(s_att[e*8+h] - m);
      s_att[e*8+h] = p; z += p;
    }
    for(int off=8; off<64; off<<=1) z += __shfl_xor(z, off, 64);
    float inv = 1.0f / (z + 1e-9f);
    for(int e=g; e<NSLOT; e+=8) s_att[e*8+h] *= inv;
  }
  __syncthreads();                        // sync5

  // ---- phase 5: agg[u=t][c] gather (wa2t/rbf regions dead -> reuse as agg) ----
  {
    int h = t >> 5;
    float a0=0.f,a1=0.f,a2=0.f,a3=0.f;
    for(int e=0;e<NSLOT;e++){
      float w = s_att[e*8 + h];
      float4 p4 = *(const float4*)(P + (size_t)s_src[e]*1024 + t*4);
      a0 += w*p4.x; a1 += w*p4.y; a2 += w*p4.z; a3 += w*p4.w;
    }
    s_mux[0*AGPAD + t] = a0;
    s_mux[1*AGPAD + t] = a1;
    s_mux[2*AGPAD + t] = a2;
    s_mux[3*AGPAD + t] = a3;
  }
  __syncthreads();                        // sync6

  // ---- phase 6: Y[d][c][k] = agg[c] @ Wo (coalesced weight loads) ----
  {
    int cp = grp*2;
    const float* g0 = s_mux + cp*AGPAD;
    const float* g1 = s_mux + (cp+1)*AGPAD;
    float x0=0.f, x1=0.f;
    for(int u=0; u<256; u+=4){
      float w0=Wo[(u+0)*128+k], w1=Wo[(u+1)*128+k], w2=Wo[(u+2)*128+k], w3=Wo[(u+3)*128+k];
      float4 a0 = *(const float4*)(g0 + u);
      float4 a1 = *(const float4*)(g1 + u);
      x0 += a0.x*w0 + a0.y*w1 + a0.z*w2 + a0.w*w3;
      x1 += a1.x*w0 + a1.y*w1 + a1.z*w2 + a1.w*w3;
    }
    Y[d*512 + cp*128 + k]     = x0;
    Y[d*512 + (cp+1)*128 + k] = x1;
  }
}

// ---------------- K5: per-node MLP chain, 4 nodes/block, 512 threads ------------
__global__ __launch_bounds__(512) void k_node(
    const float* __restrict__ rots, const float* __restrict__ trans,
    const float* __restrict__ Y,
    const float* __restrict__ Wg, const float* __restrict__ Wf1,
    const float* __restrict__ Wf2, const float* __restrict__ Wr1,
    const float* __restrict__ br1, const float* __restrict__ Wr2,
    const float* __restrict__ br2, const float* __restrict__ Wr3,
    const float* __restrict__ br3, const float* __restrict__ Wt,
    const int* __restrict__ nmask, float* __restrict__ out)
{
  __shared__ __align__(16) float s_y[4][4][128];
  __shared__ __align__(16) float s_t1[4][128];
  __shared__ __align__(16) float s_bb0[4][128];
  __shared__ __align__(16) float s_gv[4][3][128];
  __shared__ __align__(16) float s_h1[4][256];
  __shared__ __align__(16) float s_h2[4][128];
  __shared__ float s_sc[4][8];

  int b = blockIdx.x, t = threadIdx.x;
  int nd = t >> 7, k = t & 127;
  int dbase = b*4;
  int d = dbase + nd;
  for(int i=t; i<4*512; i+=512){
    int n2 = i>>9, c=(i>>7)&3, kk=i&127;
    s_y[n2][c][kk] = Y[(dbase+n2)*512 + c*128 + kk];
  }
  __syncthreads();

  float g=0.f, f1=0.f;
  for(int j=0;j<128;j+=4){
    float wg0=Wg[(j+0)*128+k], wg1=Wg[(j+1)*128+k], wg2=Wg[(j+2)*128+k], wg3=Wg[(j+3)*128+k];
    float wf0=Wf1[(j+0)*128+k], wf1_=Wf1[(j+1)*128+k], wf2_=Wf1[(j+2)*128+k], wf3=Wf1[(j+3)*128+k];
    float4 yv = *(const float4*)&s_y[nd][0][j];
    g  += yv.x*wg0 + yv.y*wg1 + yv.z*wg2 + yv.w*wg3;
    f1 += yv.x*wf0 + yv.y*wf1_ + yv.z*wf2_ + yv.w*wf3;
  }
  float gate = 1.0f/(1.0f + expf(-g));
  s_t1[nd][k] = fmaxf(f1, 0.0f);
  __syncthreads();

  float f0=0.f;
  for(int j=0;j<128;j+=4){
    float w0=Wf2[(j+0)*128+k], w1=Wf2[(j+1)*128+k], w2=Wf2[(j+2)*128+k], w3=Wf2[(j+3)*128+k];
    float4 tv = *(const float4*)&s_t1[nd][j];
    f0 += tv.x*w0 + tv.y*w1 + tv.z*w2 + tv.w*w3;
  }
  {
    float bb0 = s_y[nd][0][k] + f0;
    s_bb0[nd][k] = bb0;
    out[OUT_BB + d*512 + k] = bb0;
#pragma unroll
    for(int c=1;c<4;c++){
      float v = s_y[nd][c][k] * gate;
      s_gv[nd][c-1][k] = v;
      out[OUT_BB + d*512 + c*128 + k] = v;
    }
  }
  __syncthreads();

  float a1 = br1[k], a2 = br1[128+k];
  for(int j=0;j<128;j+=4){
    float w10=Wr1[(j+0)*256+k],     w11=Wr1[(j+1)*256+k],     w12=Wr1[(j+2)*256+k],     w13=Wr1[(j+3)*256+k];
    float w20=Wr1[(j+0)*256+128+k], w21=Wr1[(j+1)*256+128+k], w22=Wr1[(j+2)*256+128+k], w23=Wr1[(j+3)*256+128+k];
    float4 bv = *(const float4*)&s_bb0[nd][j];
    a1 += bv.x*w10 + bv.y*w11 + bv.z*w12 + bv.w*w13;
    a2 += bv.x*w20 + bv.y*w21 + bv.z*w22 + bv.w*w23;
  }
  s_h1[nd][k] = fmaxf(a1, 0.0f);
  s_h1[nd][128+k] = fmaxf(a2, 0.0f);
  __syncthreads();

  float a = br2[k];
  for(int j=0;j<256;j+=4){
    float w0=Wr2[(j+0)*128+k], w1=Wr2[(j+1)*128+k], w2=Wr2[(j+2)*128+k], w3=Wr2[(j+3)*128+k];
    float4 hv = *(const float4*)&s_h1[nd][j];
    a += hv.x*w0 + hv.y*w1 + hv.z*w2 + hv.w*w3;
  }
  s_h2[nd][k] = fmaxf(a, 0.0f);
  __syncthreads();

  if(t < 12){
    int n2 = t/3, r = t%3;
    float q = br3[r];
    for(int kk=0;kk<128;kk++) q += s_h2[n2][kk] * Wr3[kk*6 + r];
    s_sc[n2][r] = q;
  } else if(t >= 32 && t < 44){
    int q2 = t-32; int n2 = q2/3, i = q2%3;
    float s = 0.f;
    for(int kk=0;kk<128;kk++) s += s_gv[n2][i][kk] * Wt[kk];
    s_sc[n2][4+i] = s;
  }
  __syncthreads();

  if(t < 4){
    int d2 = dbase + t;
    int nz = nmask[d2];
    float q1=s_sc[t][0], q2=s_sc[t][1], q3=s_sc[t][2];
    float nrm = sqrtf(1.0f + q1*q1 + q2*q2 + q3*q3);
    float w=1.0f/nrm, x=q1/nrm, y=q2/nrm, z=q3/nrm;
    float Ru[3][3];
    Ru[0][0]=1.f-2.f*(y*y+z*z); Ru[0][1]=2.f*(x*y-w*z);     Ru[0][2]=2.f*(x*z+w*y);
    Ru[1][0]=2.f*(x*y+w*z);     Ru[1][1]=1.f-2.f*(x*x+z*z); Ru[1][2]=2.f*(y*z-w*x);
    Ru[2][0]=2.f*(x*z-w*y);     Ru[2][1]=2.f*(y*z+w*x);     Ru[2][2]=1.f-2.f*(x*x+y*y);
    for(int i=0;i<3;i++){
      for(int j=0;j<3;j++){
        float rv;
        if(nz){
          rv = rots[d2*9+i*3+0]*Ru[0][j] + rots[d2*9+i*3+1]*Ru[1][j] + rots[d2*9+i*3+2]*Ru[2][j];
        } else {
          rv = rots[d2*9+i*3+j];
        }
        out[OUT_ROT + d2*9 + i*3 + j] = rv;
      }
      float tv = trans[d2*3+i];
      out[OUT_TRANS + d2*3 + i] = nz ? (tv + s_sc[t][4+i]) : tv;
    }
  }
}

extern "C" void kernel_launch(void* const* d_in, const int* in_sizes, int n_in,
                              void* d_out, int out_size, void* d_ws, size_t ws_size,
                              hipStream_t stream)
{
  (void)in_sizes; (void)n_in; (void)out_size; (void)ws_size;
  const float* rots = (const float*)d_in[0];
  const float* trans = (const float*)d_in[1];
  const float* nf   = (const float*)d_in[2];
  const float* Wa1  = (const float*)d_in[3];
  const float* ba1  = (const float*)d_in[4];
  const float* Wa2  = (const float*)d_in[5];
  const float* Wv   = (const float*)d_in[6];
  const float* Wo   = (const float*)d_in[7];
  const float* Wg   = (const float*)d_in[8];
  const float* Wf1  = (const float*)d_in[9];
  const float* Wf2  = (const float*)d_in[10];
  const float* Wr1  = (const float*)d_in[11];
  const float* br1  = (const float*)d_in[12];
  const float* Wr2  = (const float*)d_in[13];
  const float* br2  = (const float*)d_in[14];
  const float* Wr3  = (const float*)d_in[15];
  const float* br3  = (const float*)d_in[16];
  const float* Wt   = (const float*)d_in[17];
  const int* xmask  = (const int*)d_in[19];
  const int* nmask  = (const int*)d_in[20];

  float* P = (float*)d_ws;                 // NN*1024 f32  (8 MB), layout [n][u][c]
  float* U = P + NN*1024;                  // NN*128       (1 MB)
  float* V = U + NN*128;                   // NN*128       (1 MB)
  int* srcs = (int*)(V + NN*128);          // NN*40 int    (320 KB)
  float* Y  = (float*)(srcs + NN*NFIX);    // NN*512 f32   (4 MB)
  float* Trel = Y + NN*512;                // 1023*128 f32 (0.52 MB)

  k_pretop<<<NN + 512 + 512, 256, 0, stream>>>(rots, trans, nf, Wa1, Wv,
                                               xmask, nmask, P, U, V, srcs, Trel);
  k_attn<<<NN, 256, 0, stream>>>(trans, Wa1, ba1, Wa2, Wo, U, V, P, Trel, srcs, Y);
  k_node<<<NN/4, 512, 0, stream>>>(rots, trans, Y, Wg, Wf1, Wf2,
                                   Wr1, br1, Wr2, br2, Wr3, br3, Wt,
                                   nmask, (float*)d_out);
}